// Round 12
// baseline (581.792 us; speedup 1.0000x reference)
//
#include <hip/hip_runtime.h>
#include <hip/hip_bf16.h>

// DCNConv pipeline, MI355X round 17: FUSE the offset conv into dconv.
// Round 16's split-oc confirmed the 2-barrier-per-sub event count is the
// dconv floor (occupancy 34% but slower). Remaining serial stage: k_off_v
// (~45-55us standalone VALU) while dconv's VALU idles at 27%. dconv's 800
// blocks tile pixels identically to off_v's -> each dconv block now computes
// its own 64x18 offsets in the prologue (off_v math verbatim, L2-hot hN),
// reducing through LDS aliased onto A_lds/B_lds (dead until K-loop), then
// the bilinear table reads offsets from LDS. Deletes the off_v launch and
// the 7.4MB off round-trip. dconv K-loop = r15 body verbatim (176.6us
// validated: 256oc, cheap prefetch, XCD swizzle). conv1n = r16 (swizzle).
//
// Primary ws layout (84,264,960 B) — obuf now unused, layout unchanged:
//   [0)          hN   bf16 [8][6400pix][256c] = 26,214,400 B
//   [26,214,400) (free, was off)              =  3,686,400 B
//   [29,900,800) wb2  bf16 [256][2304]        =  1,179,648 B (dconv w, tap-major)
//   [31,080,448) wb1  bf16 [256][1152]        =    589,824 B (conv1 w)
//   [31,670,272) wToff fp32 [9][256][18]      =    165,888 B
//   [31,836,160) xN   bf16 [8][25600pix][128c]= 52,428,800 B

typedef __hip_bfloat16 bf16;
typedef __attribute__((ext_vector_type(8))) short short8;
typedef __attribute__((ext_vector_type(4))) float float4v;

#define EPSBN 1e-5f

__device__ __forceinline__ float bf2f(bf16 x){ return __bfloat162float(x); }
__device__ __forceinline__ float bits2f(unsigned short u){ return __uint_as_float(((unsigned)u) << 16); }
__device__ __forceinline__ float silu_(float x){ return x / (1.f + __expf(-x)); }
__device__ __forceinline__ unsigned short f2bf_bits(float f){
    union { float f; unsigned u; } uf; uf.f = f;
    unsigned r = uf.u + 0x7fff + ((uf.u >> 16) & 1);   // RNE (finite inputs)
    return (unsigned short)(r >> 16);
}

// ---------------------------------------------------------------------------
// K0a: dconv_w [256oc][256c][9tap] fp32 -> wb2 bf16 [256oc][2304], kk = tap*256+c.
__global__ __launch_bounds__(256) void k_wdprep(const float* __restrict__ w, bf16* __restrict__ wb2)
{
    int idx = blockIdx.x * 256 + threadIdx.x;
    if (idx >= 256 * 2304) return;
    int oc  = idx / 2304;
    int r   = idx - oc * 2304;
    int tap = r >> 8;
    int c   = r & 255;
    wb2[idx] = __float2bfloat16(w[(oc * 256 + c) * 9 + tap]);
}

// K0b (primary): conv1 weights -> bf16 TAP-MAJOR [oc][tap*128+c].
__global__ __launch_bounds__(256) void k_wprep1t(const float* __restrict__ w, bf16* __restrict__ wb)
{
    int idx = blockIdx.x * 256 + threadIdx.x;      // 294,912
    if (idx >= 256 * 1152) return;
    int oc  = idx / 1152;
    int r   = idx - oc * 1152;
    int tap = r >> 7;
    int c   = r & 127;
    wb[idx] = __float2bfloat16(w[(oc * 128 + c) * 9 + tap]);
}

// K0b' (fallback): conv1 weights -> bf16, c-major [oc][c*9+tap] (round-6).
__global__ __launch_bounds__(256) void k_wprep(const float* __restrict__ w, bf16* __restrict__ wb)
{
    int idx = blockIdx.x * 256 + threadIdx.x;
    if (idx >= 256 * 1152) return;
    wb[idx] = __float2bfloat16(w[idx]);
}

// K0c: off_w [18oc][256c][9tap] fp32 -> wToff fp32 [(tap*256+c)*18 + oc].
__global__ __launch_bounds__(256) void k_woprep2(const float* __restrict__ w, float* __restrict__ wT)
{
    int idx = blockIdx.x * 256 + threadIdx.x;      // 41,472
    if (idx >= 9 * 256 * 18) return;
    int oc  = idx % 18;
    int r   = idx / 18;
    int c   = r & 255;
    int tap = r >> 8;
    wT[idx] = w[(oc * 256 + c) * 9 + tap];
}

// K0d: x NCHW fp32 -> xN NHWC bf16 via LDS tile transpose.
__global__ __launch_bounds__(256) void k_xprep(const float* __restrict__ x, bf16* __restrict__ xN)
{
    __shared__ short sm[64 * 132];                 // 16,896 B
    const int tid  = threadIdx.x;
    const int b    = blockIdx.x / 400;             // 3200 blocks
    const int pix0 = (blockIdx.x % 400) * 64;
    const int lane = tid & 63;
    const int wq   = tid >> 6;
    const float* xb = x + (size_t)b * 128 * 25600;

    #pragma unroll
    for (int i = 0; i < 32; i++){
        int c = i * 4 + wq;
        sm[lane * 132 + c] = (short)f2bf_bits(xb[c * 25600 + pix0 + lane]);
    }
    __syncthreads();

    bf16* xo = xN + ((size_t)b * 25600 + pix0) * 128;
    #pragma unroll
    for (int j = 0; j < 8; j++){
        int idx = j * 256 + tid;                   // 0..2047
        int p = idx >> 5, q = idx & 31;
        *reinterpret_cast<ushort4*>(xo + p * 128 + q * 4) =
            *reinterpret_cast<const ushort4*>(&sm[p * 132 + q * 4]);
    }
}

// ---------------------------------------------------------------------------
// K1 (primary): conv1 (3x3 s2 p1) + BN1 + SiLU, MFMA implicit GEMM on NHWC xN.
// Round-11 register-prefetch pipeline + XCD-aligned block mapping (r16).
__global__ __launch_bounds__(256) void k_conv1n(
    const bf16* __restrict__ xN, const bf16* __restrict__ wb,
    const float* __restrict__ g, const float* __restrict__ bb,
    const float* __restrict__ mm, const float* __restrict__ vv,
    bf16* __restrict__ hN)
{
    __shared__ short A_lds[256 * 40];              // 20,480 B
    __shared__ short B_lds[64 * 40];               //  5,120 B
    __shared__ unsigned short nidx[576];           //  1,152 B
    __shared__ unsigned short nmsk[576];           //  1,152 B
    __shared__ float sc_s[256], sh_s[256];         //  2,048 B

    const int tid  = threadIdx.x;
    const int b    = blockIdx.x & 7;               // XCD-aligned (800 = 8*100)
    const int pix0 = (blockIdx.x >> 3) * 64;
    const bf16* xb = xN + (size_t)b * 25600 * 128;

    {
        float scv = g[tid] * rsqrtf(vv[tid] + EPSBN);
        sc_s[tid] = scv;
        sh_s[tid] = bb[tid] - mm[tid] * scv;
    }

    for (int e = tid; e < 576; e += 256){
        int t = e & 63, k = e >> 6;
        int pix = pix0 + t;
        int oh = pix / 80, ow = pix % 80;
        int ih = 2 * oh + k / 3 - 1;
        int iw = 2 * ow + k % 3 - 1;
        nmsk[e] = ((ih | iw) >= 0) ? 1 : 0;
        nidx[e] = (unsigned short)(max(ih, 0) * 160 + max(iw, 0));
    }
    __syncthreads();

    const int t4   = tid >> 2;                     // pixel 0..63
    const int cq   = tid & 3;                      // channel octet
    const int wv   = tid >> 6;
    const int lane = tid & 63;
    const int lrow = lane & 15;
    const int quad = lane >> 4;
    const int ocA  = tid >> 2;                     // A-stage row
    const int kqA  = tid & 3;

    uint4  pa0, pa1, pa2, pa3;                     // A prefetch regs
    short8 pbv;                                    // B prefetch reg

    float4v acc[4][4];
    #pragma unroll
    for (int i = 0; i < 4; i++)
        #pragma unroll
        for (int j = 0; j < 4; j++)
            acc[i][j] = (float4v){0.f, 0.f, 0.f, 0.f};

    auto issue_pref = [&](int kc){
        const bf16* wp = wb + kc * 32 + kqA * 8;
        pa0 = *reinterpret_cast<const uint4*>(wp + (0 * 64 + ocA) * 1152);
        pa1 = *reinterpret_cast<const uint4*>(wp + (1 * 64 + ocA) * 1152);
        pa2 = *reinterpret_cast<const uint4*>(wp + (2 * 64 + ocA) * 1152);
        pa3 = *reinterpret_cast<const uint4*>(wp + (3 * 64 + ocA) * 1152);
        const int tap = kc >> 2;
        const int cb  = (kc & 3) * 32;
        const int e   = tap * 64 + t4;
        const int sp  = (int)nidx[e];
        const bool mv = nmsk[e] != 0;
        short8 v = {0, 0, 0, 0, 0, 0, 0, 0};
        if (mv) v = *reinterpret_cast<const short8*>(xb + (size_t)sp * 128 + cb + cq * 8);
        pbv = v;
    };
    auto write_stage = [&](){
        *reinterpret_cast<uint4*>(&A_lds[(0 * 64 + ocA) * 40 + kqA * 8]) = pa0;
        *reinterpret_cast<uint4*>(&A_lds[(1 * 64 + ocA) * 40 + kqA * 8]) = pa1;
        *reinterpret_cast<uint4*>(&A_lds[(2 * 64 + ocA) * 40 + kqA * 8]) = pa2;
        *reinterpret_cast<uint4*>(&A_lds[(3 * 64 + ocA) * 40 + kqA * 8]) = pa3;
        *reinterpret_cast<short8*>(&B_lds[t4 * 40 + cq * 8]) = pbv;
    };

    issue_pref(0);
    write_stage();
    __syncthreads();

    for (int kc = 0; kc < 36; kc++){
        if (kc < 35) issue_pref(kc + 1);           // in-flight across the MFMA block

        short8 af[4], bfv[4];
        #pragma unroll
        for (int i = 0; i < 4; i++){
            int row = wv * 64 + i * 16 + lrow;
            af[i] = *reinterpret_cast<const short8*>(&A_lds[row * 40 + quad * 8]);
        }
        #pragma unroll
        for (int j = 0; j < 4; j++){
            bfv[j] = *reinterpret_cast<const short8*>(&B_lds[(j * 16 + lrow) * 40 + quad * 8]);
        }
        #pragma unroll
        for (int i = 0; i < 4; i++)
            #pragma unroll
            for (int j = 0; j < 4; j++)
                acc[i][j] = __builtin_amdgcn_mfma_f32_16x16x32_bf16(af[i], bfv[j], acc[i][j], 0, 0, 0);

        if (kc < 35){
            __syncthreads();                       // all reads of kc done
            write_stage();                         // stage kc+1
            __syncthreads();                       // kc+1 ready
        }
    }

    #pragma unroll
    for (int i = 0; i < 4; i++){
        int oc0 = wv * 64 + i * 16 + quad * 4;
        float s0 = sc_s[oc0+0], h0 = sh_s[oc0+0];
        float s1 = sc_s[oc0+1], h1 = sh_s[oc0+1];
        float s2 = sc_s[oc0+2], h2 = sh_s[oc0+2];
        float s3 = sc_s[oc0+3], h3 = sh_s[oc0+3];
        #pragma unroll
        for (int j = 0; j < 4; j++){
            int pix = pix0 + j * 16 + lrow;
            ushort4 o;
            o.x = f2bf_bits(silu_(acc[i][j][0] * s0 + h0));
            o.y = f2bf_bits(silu_(acc[i][j][1] * s1 + h1));
            o.z = f2bf_bits(silu_(acc[i][j][2] * s2 + h2));
            o.w = f2bf_bits(silu_(acc[i][j][3] * s3 + h3));
            *reinterpret_cast<ushort4*>(hN + ((size_t)b * 6400 + pix) * 256 + oc0) = o;
        }
    }
}

// K1 (fallback): round-6 conv1 on NCHW fp32 x (validated), verbatim.
__global__ __launch_bounds__(256) void k_conv1(
    const float* __restrict__ x, const bf16* __restrict__ wb,
    const float* __restrict__ g, const float* __restrict__ bb,
    const float* __restrict__ mm, const float* __restrict__ vv,
    bf16* __restrict__ hN)
{
    __shared__ short A_lds[256 * 40];
    __shared__ short B_lds[64 * 40];
    __shared__ float sc_s[256], sh_s[256];

    const int tid  = threadIdx.x;
    const int b    = blockIdx.x / 100;
    const int pix0 = (blockIdx.x % 100) * 64;
    const float* xb = x + b * (128 * 25600);

    {
        float scv = g[tid] * rsqrtf(vv[tid] + EPSBN);
        sc_s[tid] = scv;
        sh_s[tid] = bb[tid] - mm[tid] * scv;
    }

    const int k_in = tid & 31;
    const int prow = tid >> 5;
    int oh8[8], ow8[8];
    #pragma unroll
    for (int p = 0; p < 8; p++){
        int pix = pix0 + prow + p * 8;
        oh8[p] = pix / 80; ow8[p] = pix % 80;
    }

    const int wv   = tid >> 6;
    const int lane = tid & 63;
    const int lrow = lane & 15;
    const int quad = lane >> 4;

    float4v acc[4][4];
    #pragma unroll
    for (int i = 0; i < 4; i++)
        #pragma unroll
        for (int j = 0; j < 4; j++)
            acc[i][j] = (float4v){0.f, 0.f, 0.f, 0.f};

    for (int kc = 0; kc < 36; kc++){
        const int k0 = kc * 32;
        __syncthreads();

        #pragma unroll
        for (int p2 = 0; p2 < 4; p2++){
            int idx = p2 * 256 + tid;
            int oc  = idx >> 2;
            int kq  = idx & 3;
            *reinterpret_cast<uint4*>(&A_lds[oc * 40 + kq * 8]) =
                *reinterpret_cast<const uint4*>(wb + oc * 1152 + k0 + kq * 8);
        }

        {
            int kk  = k0 + k_in;
            int c   = kk / 9;
            int tap = kk - 9 * c;
            int kh  = tap / 3 - 1;
            int kw  = tap - 3 * (tap / 3) - 1;
            const float* xc = xb + c * 25600;
            #pragma unroll
            for (int p = 0; p < 8; p++){
                int ih = 2 * oh8[p] + kh;
                int iw = 2 * ow8[p] + kw;
                float v = 0.f;
                if ((ih | iw) >= 0) v = xc[ih * 160 + iw];
                B_lds[(prow + p * 8) * 40 + k_in] = (short)f2bf_bits(v);
            }
        }
        __syncthreads();

        short8 af[4], bfv[4];
        #pragma unroll
        for (int i = 0; i < 4; i++){
            int row = wv * 64 + i * 16 + lrow;
            af[i] = *reinterpret_cast<const short8*>(&A_lds[row * 40 + quad * 8]);
        }
        #pragma unroll
        for (int j = 0; j < 4; j++){
            bfv[j] = *reinterpret_cast<const short8*>(&B_lds[(j * 16 + lrow) * 40 + quad * 8]);
        }
        #pragma unroll
        for (int i = 0; i < 4; i++)
            #pragma unroll
            for (int j = 0; j < 4; j++)
                acc[i][j] = __builtin_amdgcn_mfma_f32_16x16x32_bf16(af[i], bfv[j], acc[i][j], 0, 0, 0);
    }

    #pragma unroll
    for (int i = 0; i < 4; i++){
        int oc0 = wv * 64 + i * 16 + quad * 4;
        float s0 = sc_s[oc0+0], h0 = sh_s[oc0+0];
        float s1 = sc_s[oc0+1], h1 = sh_s[oc0+1];
        float s2 = sc_s[oc0+2], h2 = sh_s[oc0+2];
        float s3 = sc_s[oc0+3], h3 = sh_s[oc0+3];
        #pragma unroll
        for (int j = 0; j < 4; j++){
            int pix = pix0 + j * 16 + lrow;
            ushort4 o;
            o.x = f2bf_bits(silu_(acc[i][j][0] * s0 + h0));
            o.y = f2bf_bits(silu_(acc[i][j][1] * s1 + h1));
            o.z = f2bf_bits(silu_(acc[i][j][2] * s2 + h2));
            o.w = f2bf_bits(silu_(acc[i][j][3] * s3 + h3));
            *reinterpret_cast<ushort4*>(hN + (b * 6400 + pix) * 256 + oc0) = o;
        }
    }
}

// ---------------------------------------------------------------------------
// K3: deform conv MFMA on NHWC h — round-17: r15 body (validated 176.6us)
// with the OFFSET CONV FUSED into the prologue. Phase A: off_v math verbatim
// per block (4 waves x 64ch partial acc) -> red (aliased on A_lds). Phase B:
// reduce + bias -> offs[18][64] (aliased on B_lds). Phase C: bilinear table
// from offs (LDS, not global). Phase D: r15 K-loop verbatim (A_lds/B_lds
// reused after the phase-C barrier).
__global__ __launch_bounds__(256) void k_dconv_nhwc(
    const bf16* __restrict__ hN, const float* __restrict__ wT,
    const float* __restrict__ obias, const bf16* __restrict__ wb2,
    const float* __restrict__ g, const float* __restrict__ bb,
    const float* __restrict__ mm, const float* __restrict__ vv,
    float* __restrict__ out)
{
    __shared__ short   A_lds[256 * 40];            // 20,480 B (prologue alias: red 18,432 B)
    __shared__ short   B_lds[64 * 40];             //  5,120 B (prologue alias: offs 4,608 B)
    __shared__ ushort4 sidxu[576];                 //  4,608 B
    __shared__ ushort4 swtu [576];                 //  4,608 B
    __shared__ float   sc_s[256], sh_s[256];       //  2,048 B  -> 36,864 B total

    const int tid  = threadIdx.x;
    const int b    = blockIdx.x & 7;               // XCD-aligned (800 = 8*100)
    const int pix0 = (blockIdx.x >> 3) * 64;
    const bf16* hb = hN + b * (6400 * 256);

    float* red  = reinterpret_cast<float*>(A_lds); // [4][18][64] partials
    float* offs = reinterpret_cast<float*>(B_lds); // [18][64] final offsets

    {
        float scv = g[tid] * rsqrtf(vv[tid] + EPSBN);
        sc_s[tid] = scv;
        sh_s[tid] = bb[tid] - mm[tid] * scv;
    }

    // ---- phase A: offset conv partials (off_v verbatim, block-local) ----
    {
        const int lane  = tid & 63;
        const int wvv   = tid >> 6;
        const int cbase = __builtin_amdgcn_readfirstlane(wvv << 6);
        const int pix = pix0 + lane;
        const int oh  = pix / 80, ow = pix % 80;

        float oacc[18];
        #pragma unroll
        for (int o = 0; o < 18; o++) oacc[o] = 0.f;

        for (int tap = 0; tap < 9; tap++){
            int ih = oh + tap / 3 - 1, iw = ow + tap % 3 - 1;
            bool val = ((unsigned)ih < 80u) && ((unsigned)iw < 80u);
            int  sp  = min(max(ih, 0), 79) * 80 + min(max(iw, 0), 79);
            float m  = val ? 1.f : 0.f;
            const bf16*  hp = hb + (size_t)sp * 256 + cbase;
            const float* wp = wT + (tap * 256 + cbase) * 18;
            for (int cs = 0; cs < 64; cs += 4){
                ushort4 hv = *reinterpret_cast<const ushort4*>(hp + cs);
                float h0 = bits2f(hv.x) * m, h1 = bits2f(hv.y) * m,
                      h2 = bits2f(hv.z) * m, h3 = bits2f(hv.w) * m;
                const float* w0 = wp + cs * 18;
                #pragma unroll
                for (int o = 0; o < 18; o++){
                    oacc[o] += h0 * w0[o] + h1 * w0[18 + o] + h2 * w0[36 + o] + h3 * w0[54 + o];
                }
            }
        }
        #pragma unroll
        for (int o = 0; o < 18; o++)
            red[(wvv * 18 + o) * 64 + lane] = oacc[o];
    }
    __syncthreads();

    // ---- phase B: reduce partials + bias -> offs[18][64] ----
    for (int i = tid; i < 18 * 64; i += 256){
        int o = i >> 6, p = i & 63;
        offs[i] = red[(0 * 18 + o) * 64 + p] + red[(1 * 18 + o) * 64 + p]
                + red[(2 * 18 + o) * 64 + p] + red[(3 * 18 + o) * 64 + p] + obias[o];
    }
    __syncthreads();

    // ---- phase C: bilinear table from LDS offsets ----
    for (int e = tid; e < 576; e += 256){
        int t = e & 63, k = e >> 6;
        int pix = pix0 + t;
        int oh = pix / 80, ow = pix % 80;
        int kh = k / 3, kw = k % 3;
        float oy = offs[(2 * k    ) * 64 + t];
        float ox = offs[(2 * k + 1) * 64 + t];
        float py = (float)(oh + kh - 1) + oy;
        float px = (float)(ow + kw - 1) + ox;
        float y0f = floorf(py), x0f = floorf(px);
        float wy1 = py - y0f,  wx1 = px - x0f;
        int y0 = (int)y0f, x0 = (int)x0f;
        unsigned short ii[4], ww[4];
        #pragma unroll
        for (int cy = 0; cy < 2; cy++){
            int   yy = y0 + cy;
            float wy = cy ? wy1 : 1.f - wy1;
            bool  vy = (yy >= 0) && (yy < 80);
            int   yc = min(max(yy, 0), 79);
            #pragma unroll
            for (int cx = 0; cx < 2; cx++){
                int   xx = x0 + cx;
                float wx = cx ? wx1 : 1.f - wx1;
                bool  vx = (xx >= 0) && (xx < 80);
                int   xc = min(max(xx, 0), 79);
                int ci = cy * 2 + cx;
                ii[ci] = (unsigned short)(yc * 80 + xc);
                ww[ci] = f2bf_bits((vy && vx) ? wy * wx : 0.f);
            }
        }
        ushort4 iv; iv.x = ii[0]; iv.y = ii[1]; iv.z = ii[2]; iv.w = ii[3];
        ushort4 wv_; wv_.x = ww[0]; wv_.y = ww[1]; wv_.z = ww[2]; wv_.w = ww[3];
        sidxu[e] = iv;
        swtu [e] = wv_;
    }
    __syncthreads();                               // offs dead; A/B_lds free

    // ---- phase D: r15 K-loop verbatim ----
    const int t4   = tid >> 2;                     // pixel 0..63
    const int cq   = tid & 3;                      // channel octet (8 contiguous ch in sub)
    const int wv   = tid >> 6;
    const int lane = tid & 63;
    const int lrow = lane & 15;
    const int quad = lane >> 4;
    const int ocA  = tid >> 2;                     // A-stage row base
    const int kqA  = tid & 3;

    const bf16* wA = wb2 + (size_t)ocA * 2304 + kqA * 8;

    float w0, w1, w2, w3;
    const bf16 *p0, *p1, *p2, *p3;
    auto load_tap_state = [&](int tap){
        const int e = tap * 64 + t4;
        ushort4 ipk = sidxu[e];
        ushort4 wpk = swtu[e];
        w0 = bits2f(wpk.x); w1 = bits2f(wpk.y);
        w2 = bits2f(wpk.z); w3 = bits2f(wpk.w);
        p0 = hb + (int)ipk.x * 256 + cq * 8;
        p1 = hb + (int)ipk.y * 256 + cq * 8;
        p2 = hb + (int)ipk.z * 256 + cq * 8;
        p3 = hb + (int)ipk.w * 256 + cq * 8;
    };

    uint4  pa0, pa1, pa2, pa3;                     // A prefetch regs
    short8 pb0, pb1, pb2, pb3;                     // B gather prefetch regs

    auto issue_pref = [&](int kc){
        const bf16* wp = wA + kc * 32;
        pa0 = *reinterpret_cast<const uint4*>(wp);
        pa1 = *reinterpret_cast<const uint4*>(wp + (size_t)64 * 2304);
        pa2 = *reinterpret_cast<const uint4*>(wp + (size_t)128 * 2304);
        pa3 = *reinterpret_cast<const uint4*>(wp + (size_t)192 * 2304);
        const int co = (kc & 7) * 32;
        pb0 = *reinterpret_cast<const short8*>(p0 + co);
        pb1 = *reinterpret_cast<const short8*>(p1 + co);
        pb2 = *reinterpret_cast<const short8*>(p2 + co);
        pb3 = *reinterpret_cast<const short8*>(p3 + co);
    };

    float4v acc[4][4];
    #pragma unroll
    for (int i = 0; i < 4; i++)
        #pragma unroll
        for (int j = 0; j < 4; j++)
            acc[i][j] = (float4v){0.f, 0.f, 0.f, 0.f};

    load_tap_state(0);
    issue_pref(0);

    for (int tap = 0; tap < 9; tap++){
        for (int sub = 0; sub < 8; sub++){
            const int kc = tap * 8 + sub;

            // blend for kc (waits pb vmcnt — issued one MFMA block ago)
            short8 ob;
            #pragma unroll
            for (int el = 0; el < 8; el++){
                float f = w0 * bits2f((unsigned short)pb0[el])
                        + w1 * bits2f((unsigned short)pb1[el])
                        + w2 * bits2f((unsigned short)pb2[el])
                        + w3 * bits2f((unsigned short)pb3[el]);
                ob[el] = (short)f2bf_bits(f);
            }

            __syncthreads();                       // prev iter's ds_reads done

            // stage kc
            *reinterpret_cast<uint4*>(&A_lds[(0 * 64 + ocA) * 40 + kqA * 8]) = pa0;
            *reinterpret_cast<uint4*>(&A_lds[(1 * 64 + ocA) * 40 + kqA * 8]) = pa1;
            *reinterpret_cast<uint4*>(&A_lds[(2 * 64 + ocA) * 40 + kqA * 8]) = pa2;
            *reinterpret_cast<uint4*>(&A_lds[(3 * 64 + ocA) * 40 + kqA * 8]) = pa3;
            *reinterpret_cast<short8*>(&B_lds[t4 * 40 + cq * 8]) = ob;

            __syncthreads();                       // kc staged

            // prefetch kc+1 (cheap: imm offsets; new tap state once per 8)
            if (kc < 71){
                if (sub == 7) load_tap_state(tap + 1);
                issue_pref(kc + 1);
            }

            // MFMA for kc — covers the just-issued loads
            short8 af[4], bfv[4];
            #pragma unroll
            for (int i = 0; i < 4; i++){
                int row = wv * 64 + i * 16 + lrow;
                af[i] = *reinterpret_cast<const short8*>(&A_lds[row * 40 + quad * 8]);
            }
            #pragma unroll
            for (int j = 0; j < 4; j++){
                bfv[j] = *reinterpret_cast<const short8*>(&B_lds[(j * 16 + lrow) * 40 + quad * 8]);
            }
            #pragma unroll
            for (int i = 0; i < 4; i++)
                #pragma unroll
                for (int j = 0; j < 4; j++)
                    acc[i][j] = __builtin_amdgcn_mfma_f32_16x16x32_bf16(af[i], bfv[j], acc[i][j], 0, 0, 0);
        }
    }

    #pragma unroll
    for (int i = 0; i < 4; i++){
        #pragma unroll
        for (int r = 0; r < 4; r++){
            int oc = wv * 64 + i * 16 + quad * 4 + r;
            float scv = sc_s[oc], shv = sh_s[oc];
            #pragma unroll
            for (int j = 0; j < 4; j++){
                int pix = pix0 + j * 16 + lrow;
                out[(b * 256 + oc) * 6400 + pix] = silu_(acc[i][j][r] * scv + shv);
            }
        }
    }
}

// ---------------------------------------------------------------------------
extern "C" void kernel_launch(void* const* d_in, const int* in_sizes, int n_in,
                              void* d_out, int out_size, void* d_ws, size_t ws_size,
                              hipStream_t stream)
{
    (void)in_sizes; (void)n_in; (void)out_size;

    const float* x  = (const float*)d_in[0];
    const float* w1 = (const float*)d_in[1];
    const float* g1 = (const float*)d_in[2];
    const float* b1 = (const float*)d_in[3];
    const float* m1 = (const float*)d_in[4];
    const float* v1 = (const float*)d_in[5];
    const float* wo = (const float*)d_in[6];
    const float* bo = (const float*)d_in[7];
    const float* wd = (const float*)d_in[8];
    const float* g2 = (const float*)d_in[9];
    const float* b2 = (const float*)d_in[10];
    const float* m2 = (const float*)d_in[11];
    const float* v2 = (const float*)d_in[12];
    float* outp = (float*)d_out;

    char*  wsb  = (char*)d_ws;
    bf16*  hNb  = (bf16*) wsb;                      // 26,214,400 B
    bf16*  wb2b = (bf16*) (wsb + 29900800);         //  1,179,648 B
    bf16*  wbb  = (bf16*) (wsb + 31080448);         //    589,824 B
    float* wTof = (float*)(wsb + 31670272);         //    165,888 B
    bf16*  xNb  = (bf16*) (wsb + 31836160);         // 52,428,800 B

    const size_t need_primary = 84264960;

    hipLaunchKernelGGL(k_wdprep,  dim3(2304), dim3(256), 0, stream, wd, wb2b);
    hipLaunchKernelGGL(k_woprep2, dim3(162),  dim3(256), 0, stream, wo, wTof);

    if (ws_size >= need_primary){
        hipLaunchKernelGGL(k_wprep1t, dim3(1152), dim3(256), 0, stream, w1, wbb);
        hipLaunchKernelGGL(k_xprep,   dim3(3200), dim3(256), 0, stream, x, xNb);
        hipLaunchKernelGGL(k_conv1n,  dim3(800),  dim3(256), 0, stream, xNb, wbb, g1, b1, m1, v1, hNb);
    } else {
        hipLaunchKernelGGL(k_wprep,   dim3(1152), dim3(256), 0, stream, w1, wbb);
        hipLaunchKernelGGL(k_conv1,   dim3(800),  dim3(256), 0, stream, x, wbb, g1, b1, m1, v1, hNb);
    }

    hipLaunchKernelGGL(k_dconv_nhwc, dim3(800), dim3(256), 0, stream,
                       hNb, wTof, bo, wb2b, g2, b2, m2, v2, outp);
}

// Round 13
// 474.885 us; speedup vs baseline: 1.2251x; 1.2251x over previous
//
#include <hip/hip_runtime.h>
#include <hip/hip_bf16.h>

// DCNConv pipeline, MI355X round 18: offset conv rewritten as BARRIER-FREE
// MFMA (k_off_m). Round 17's fusion failure exposed k_off_v = ~141us (2nd
// largest kernel, 5x its VALU floor). As a GEMM [18oc]x[2304K]x[51200pix]
// with NHWC h and tap-major K, the MFMA B-fragment (8 contiguous channels
// at the lane's tap-sample pixel) is ONE masked 16B global load — no LDS,
// no barriers, no blend. A-fragments from fragment-major repacked off_w
// (oc padded 18->32, 2 MFMA/chunk). Per wave: 16 pix x 18 oc, 72 chunks.
// dconv reverted to r15-exact (176.6us validated); conv1n keeps r16 swizzle.
//
// Primary ws layout (84,264,960 B):
//   [0)          hN    bf16 [8][6400pix][256c] = 26,214,400 B
//   [26,214,400) off   fp32 [8][18][6400]      =  3,686,400 B
//   [29,900,800) wb2   bf16 [256][2304]        =  1,179,648 B (dconv w, tap-major)
//   [31,080,448) wb1   bf16 [256][1152]        =    589,824 B (conv1 w)
//   [31,670,272) wToffm bf16 [2][72][512]      =    147,456 B (off w, MFMA-fragment-major)
//   [31,836,160) xN    bf16 [8][25600pix][128c]= 52,428,800 B

typedef __hip_bfloat16 bf16;
typedef __attribute__((ext_vector_type(8))) short short8;
typedef __attribute__((ext_vector_type(4))) float float4v;

#define EPSBN 1e-5f

__device__ __forceinline__ float bf2f(bf16 x){ return __bfloat162float(x); }
__device__ __forceinline__ float bits2f(unsigned short u){ return __uint_as_float(((unsigned)u) << 16); }
__device__ __forceinline__ float silu_(float x){ return x / (1.f + __expf(-x)); }
__device__ __forceinline__ unsigned short f2bf_bits(float f){
    union { float f; unsigned u; } uf; uf.f = f;
    unsigned r = uf.u + 0x7fff + ((uf.u >> 16) & 1);   // RNE (finite inputs)
    return (unsigned short)(r >> 16);
}

// ---------------------------------------------------------------------------
// K0a: dconv_w [256oc][256c][9tap] fp32 -> wb2 bf16 [256oc][2304], kk = tap*256+c.
__global__ __launch_bounds__(256) void k_wdprep(const float* __restrict__ w, bf16* __restrict__ wb2)
{
    int idx = blockIdx.x * 256 + threadIdx.x;
    if (idx >= 256 * 2304) return;
    int oc  = idx / 2304;
    int r   = idx - oc * 2304;
    int tap = r >> 8;
    int c   = r & 255;
    wb2[idx] = __float2bfloat16(w[(oc * 256 + c) * 9 + tap]);
}

// K0b (primary): conv1 weights -> bf16 TAP-MAJOR [oc][tap*128+c].
__global__ __launch_bounds__(256) void k_wprep1t(const float* __restrict__ w, bf16* __restrict__ wb)
{
    int idx = blockIdx.x * 256 + threadIdx.x;      // 294,912
    if (idx >= 256 * 1152) return;
    int oc  = idx / 1152;
    int r   = idx - oc * 1152;
    int tap = r >> 7;
    int c   = r & 127;
    wb[idx] = __float2bfloat16(w[(oc * 128 + c) * 9 + tap]);
}

// K0b' (fallback): conv1 weights -> bf16, c-major [oc][c*9+tap] (round-6).
__global__ __launch_bounds__(256) void k_wprep(const float* __restrict__ w, bf16* __restrict__ wb)
{
    int idx = blockIdx.x * 256 + threadIdx.x;
    if (idx >= 256 * 1152) return;
    wb[idx] = __float2bfloat16(w[idx]);
}

// K0c: off_w [18oc][256c][9tap] fp32 -> wToffm bf16 MFMA-FRAGMENT-MAJOR:
//   wm[(half*72 + kc)*512 + lane*8 + j] = W[oc][kk], oc = half*16 + (lane&15),
//   kk = kc*32 + (lane>>4)*8 + j (tap = kk>>8, c = kk&255); oc>=18 -> 0.
// Each 16oc x 32k fragment is a contiguous 1KB block; lane reads 16B at lane*16.
__global__ __launch_bounds__(256) void k_woprepm(const float* __restrict__ w, bf16* __restrict__ wm)
{
    int idx = blockIdx.x * 256 + threadIdx.x;      // 73,728
    if (idx >= 2 * 72 * 512) return;
    int j    = idx & 7;
    int lane = (idx >> 3) & 63;
    int frag = idx >> 9;                           // 0..143
    int half = frag / 72;
    int kc   = frag - half * 72;
    int oc   = half * 16 + (lane & 15);
    int kk   = kc * 32 + (lane >> 4) * 8 + j;
    int tap  = kk >> 8;
    int c    = kk & 255;
    float v  = (oc < 18) ? w[(oc * 256 + c) * 9 + tap] : 0.f;
    wm[idx] = __float2bfloat16(v);
}

// K0d: x NCHW fp32 -> xN NHWC bf16 via LDS tile transpose.
__global__ __launch_bounds__(256) void k_xprep(const float* __restrict__ x, bf16* __restrict__ xN)
{
    __shared__ short sm[64 * 132];                 // 16,896 B
    const int tid  = threadIdx.x;
    const int b    = blockIdx.x / 400;             // 3200 blocks
    const int pix0 = (blockIdx.x % 400) * 64;
    const int lane = tid & 63;
    const int wq   = tid >> 6;
    const float* xb = x + (size_t)b * 128 * 25600;

    #pragma unroll
    for (int i = 0; i < 32; i++){
        int c = i * 4 + wq;
        sm[lane * 132 + c] = (short)f2bf_bits(xb[c * 25600 + pix0 + lane]);
    }
    __syncthreads();

    bf16* xo = xN + ((size_t)b * 25600 + pix0) * 128;
    #pragma unroll
    for (int j = 0; j < 8; j++){
        int idx = j * 256 + tid;                   // 0..2047
        int p = idx >> 5, q = idx & 31;
        *reinterpret_cast<ushort4*>(xo + p * 128 + q * 4) =
            *reinterpret_cast<const ushort4*>(&sm[p * 132 + q * 4]);
    }
}

// ---------------------------------------------------------------------------
// K1 (primary): conv1 (3x3 s2 p1) + BN1 + SiLU, MFMA implicit GEMM on NHWC xN.
// Round-11 register-prefetch pipeline + XCD-aligned block mapping (r16).
__global__ __launch_bounds__(256) void k_conv1n(
    const bf16* __restrict__ xN, const bf16* __restrict__ wb,
    const float* __restrict__ g, const float* __restrict__ bb,
    const float* __restrict__ mm, const float* __restrict__ vv,
    bf16* __restrict__ hN)
{
    __shared__ short A_lds[256 * 40];              // 20,480 B
    __shared__ short B_lds[64 * 40];               //  5,120 B
    __shared__ unsigned short nidx[576];           //  1,152 B
    __shared__ unsigned short nmsk[576];           //  1,152 B
    __shared__ float sc_s[256], sh_s[256];         //  2,048 B

    const int tid  = threadIdx.x;
    const int b    = blockIdx.x & 7;               // XCD-aligned (800 = 8*100)
    const int pix0 = (blockIdx.x >> 3) * 64;
    const bf16* xb = xN + (size_t)b * 25600 * 128;

    {
        float scv = g[tid] * rsqrtf(vv[tid] + EPSBN);
        sc_s[tid] = scv;
        sh_s[tid] = bb[tid] - mm[tid] * scv;
    }

    for (int e = tid; e < 576; e += 256){
        int t = e & 63, k = e >> 6;
        int pix = pix0 + t;
        int oh = pix / 80, ow = pix % 80;
        int ih = 2 * oh + k / 3 - 1;
        int iw = 2 * ow + k % 3 - 1;
        nmsk[e] = ((ih | iw) >= 0) ? 1 : 0;
        nidx[e] = (unsigned short)(max(ih, 0) * 160 + max(iw, 0));
    }
    __syncthreads();

    const int t4   = tid >> 2;                     // pixel 0..63
    const int cq   = tid & 3;                      // channel octet
    const int wv   = tid >> 6;
    const int lane = tid & 63;
    const int lrow = lane & 15;
    const int quad = lane >> 4;
    const int ocA  = tid >> 2;                     // A-stage row
    const int kqA  = tid & 3;

    uint4  pa0, pa1, pa2, pa3;                     // A prefetch regs
    short8 pbv;                                    // B prefetch reg

    float4v acc[4][4];
    #pragma unroll
    for (int i = 0; i < 4; i++)
        #pragma unroll
        for (int j = 0; j < 4; j++)
            acc[i][j] = (float4v){0.f, 0.f, 0.f, 0.f};

    auto issue_pref = [&](int kc){
        const bf16* wp = wb + kc * 32 + kqA * 8;
        pa0 = *reinterpret_cast<const uint4*>(wp + (0 * 64 + ocA) * 1152);
        pa1 = *reinterpret_cast<const uint4*>(wp + (1 * 64 + ocA) * 1152);
        pa2 = *reinterpret_cast<const uint4*>(wp + (2 * 64 + ocA) * 1152);
        pa3 = *reinterpret_cast<const uint4*>(wp + (3 * 64 + ocA) * 1152);
        const int tap = kc >> 2;
        const int cb  = (kc & 3) * 32;
        const int e   = tap * 64 + t4;
        const int sp  = (int)nidx[e];
        const bool mv = nmsk[e] != 0;
        short8 v = {0, 0, 0, 0, 0, 0, 0, 0};
        if (mv) v = *reinterpret_cast<const short8*>(xb + (size_t)sp * 128 + cb + cq * 8);
        pbv = v;
    };
    auto write_stage = [&](){
        *reinterpret_cast<uint4*>(&A_lds[(0 * 64 + ocA) * 40 + kqA * 8]) = pa0;
        *reinterpret_cast<uint4*>(&A_lds[(1 * 64 + ocA) * 40 + kqA * 8]) = pa1;
        *reinterpret_cast<uint4*>(&A_lds[(2 * 64 + ocA) * 40 + kqA * 8]) = pa2;
        *reinterpret_cast<uint4*>(&A_lds[(3 * 64 + ocA) * 40 + kqA * 8]) = pa3;
        *reinterpret_cast<short8*>(&B_lds[t4 * 40 + cq * 8]) = pbv;
    };

    issue_pref(0);
    write_stage();
    __syncthreads();

    for (int kc = 0; kc < 36; kc++){
        if (kc < 35) issue_pref(kc + 1);           // in-flight across the MFMA block

        short8 af[4], bfv[4];
        #pragma unroll
        for (int i = 0; i < 4; i++){
            int row = wv * 64 + i * 16 + lrow;
            af[i] = *reinterpret_cast<const short8*>(&A_lds[row * 40 + quad * 8]);
        }
        #pragma unroll
        for (int j = 0; j < 4; j++){
            bfv[j] = *reinterpret_cast<const short8*>(&B_lds[(j * 16 + lrow) * 40 + quad * 8]);
        }
        #pragma unroll
        for (int i = 0; i < 4; i++)
            #pragma unroll
            for (int j = 0; j < 4; j++)
                acc[i][j] = __builtin_amdgcn_mfma_f32_16x16x32_bf16(af[i], bfv[j], acc[i][j], 0, 0, 0);

        if (kc < 35){
            __syncthreads();                       // all reads of kc done
            write_stage();                         // stage kc+1
            __syncthreads();                       // kc+1 ready
        }
    }

    #pragma unroll
    for (int i = 0; i < 4; i++){
        int oc0 = wv * 64 + i * 16 + quad * 4;
        float s0 = sc_s[oc0+0], h0 = sh_s[oc0+0];
        float s1 = sc_s[oc0+1], h1 = sh_s[oc0+1];
        float s2 = sc_s[oc0+2], h2 = sh_s[oc0+2];
        float s3 = sc_s[oc0+3], h3 = sh_s[oc0+3];
        #pragma unroll
        for (int j = 0; j < 4; j++){
            int pix = pix0 + j * 16 + lrow;
            ushort4 o;
            o.x = f2bf_bits(silu_(acc[i][j][0] * s0 + h0));
            o.y = f2bf_bits(silu_(acc[i][j][1] * s1 + h1));
            o.z = f2bf_bits(silu_(acc[i][j][2] * s2 + h2));
            o.w = f2bf_bits(silu_(acc[i][j][3] * s3 + h3));
            *reinterpret_cast<ushort4*>(hN + ((size_t)b * 6400 + pix) * 256 + oc0) = o;
        }
    }
}

// K1 (fallback): round-6 conv1 on NCHW fp32 x (validated), verbatim.
__global__ __launch_bounds__(256) void k_conv1(
    const float* __restrict__ x, const bf16* __restrict__ wb,
    const float* __restrict__ g, const float* __restrict__ bb,
    const float* __restrict__ mm, const float* __restrict__ vv,
    bf16* __restrict__ hN)
{
    __shared__ short A_lds[256 * 40];
    __shared__ short B_lds[64 * 40];
    __shared__ float sc_s[256], sh_s[256];

    const int tid  = threadIdx.x;
    const int b    = blockIdx.x / 100;
    const int pix0 = (blockIdx.x % 100) * 64;
    const float* xb = x + b * (128 * 25600);

    {
        float scv = g[tid] * rsqrtf(vv[tid] + EPSBN);
        sc_s[tid] = scv;
        sh_s[tid] = bb[tid] - mm[tid] * scv;
    }

    const int k_in = tid & 31;
    const int prow = tid >> 5;
    int oh8[8], ow8[8];
    #pragma unroll
    for (int p = 0; p < 8; p++){
        int pix = pix0 + prow + p * 8;
        oh8[p] = pix / 80; ow8[p] = pix % 80;
    }

    const int wv   = tid >> 6;
    const int lane = tid & 63;
    const int lrow = lane & 15;
    const int quad = lane >> 4;

    float4v acc[4][4];
    #pragma unroll
    for (int i = 0; i < 4; i++)
        #pragma unroll
        for (int j = 0; j < 4; j++)
            acc[i][j] = (float4v){0.f, 0.f, 0.f, 0.f};

    for (int kc = 0; kc < 36; kc++){
        const int k0 = kc * 32;
        __syncthreads();

        #pragma unroll
        for (int p2 = 0; p2 < 4; p2++){
            int idx = p2 * 256 + tid;
            int oc  = idx >> 2;
            int kq  = idx & 3;
            *reinterpret_cast<uint4*>(&A_lds[oc * 40 + kq * 8]) =
                *reinterpret_cast<const uint4*>(wb + oc * 1152 + k0 + kq * 8);
        }

        {
            int kk  = k0 + k_in;
            int c   = kk / 9;
            int tap = kk - 9 * c;
            int kh  = tap / 3 - 1;
            int kw  = tap - 3 * (tap / 3) - 1;
            const float* xc = xb + c * 25600;
            #pragma unroll
            for (int p = 0; p < 8; p++){
                int ih = 2 * oh8[p] + kh;
                int iw = 2 * ow8[p] + kw;
                float v = 0.f;
                if ((ih | iw) >= 0) v = xc[ih * 160 + iw];
                B_lds[(prow + p * 8) * 40 + k_in] = (short)f2bf_bits(v);
            }
        }
        __syncthreads();

        short8 af[4], bfv[4];
        #pragma unroll
        for (int i = 0; i < 4; i++){
            int row = wv * 64 + i * 16 + lrow;
            af[i] = *reinterpret_cast<const short8*>(&A_lds[row * 40 + quad * 8]);
        }
        #pragma unroll
        for (int j = 0; j < 4; j++){
            bfv[j] = *reinterpret_cast<const short8*>(&B_lds[(j * 16 + lrow) * 40 + quad * 8]);
        }
        #pragma unroll
        for (int i = 0; i < 4; i++)
            #pragma unroll
            for (int j = 0; j < 4; j++)
                acc[i][j] = __builtin_amdgcn_mfma_f32_16x16x32_bf16(af[i], bfv[j], acc[i][j], 0, 0, 0);
    }

    #pragma unroll
    for (int i = 0; i < 4; i++){
        int oc0 = wv * 64 + i * 16 + quad * 4;
        float s0 = sc_s[oc0+0], h0 = sh_s[oc0+0];
        float s1 = sc_s[oc0+1], h1 = sh_s[oc0+1];
        float s2 = sc_s[oc0+2], h2 = sh_s[oc0+2];
        float s3 = sc_s[oc0+3], h3 = sh_s[oc0+3];
        #pragma unroll
        for (int j = 0; j < 4; j++){
            int pix = pix0 + j * 16 + lrow;
            ushort4 o;
            o.x = f2bf_bits(silu_(acc[i][j][0] * s0 + h0));
            o.y = f2bf_bits(silu_(acc[i][j][1] * s1 + h1));
            o.z = f2bf_bits(silu_(acc[i][j][2] * s2 + h2));
            o.w = f2bf_bits(silu_(acc[i][j][3] * s3 + h3));
            *reinterpret_cast<ushort4*>(hN + (b * 6400 + pix) * 256 + oc0) = o;
        }
    }
}

// ---------------------------------------------------------------------------
// K2: offset conv as barrier-free MFMA. Per wave: 16 pixels x 18 oc (padded
// 32), 72 K-chunks. B-fragment = one masked 16B load from hN (lane: pixel
// l&15, k-slice (l>>4)*8 contiguous channels at the tap sample). A-fragments
// = coalesced 16B/lane from fragment-major wToffm. No LDS, no barriers.
__global__ __launch_bounds__(256) void k_off_m(
    const bf16* __restrict__ hN, const bf16* __restrict__ wm,
    const float* __restrict__ bias, float* __restrict__ off)
{
    const int tid  = threadIdx.x;
    const int b    = blockIdx.x & 7;               // XCD-aligned (800 = 8*100)
    const int pix0 = (blockIdx.x >> 3) * 64 + (tid >> 6) * 16;  // wave's 16 pixels
    const int lane = tid & 63;
    const int l15  = lane & 15;
    const int ksl  = lane >> 4;
    const bf16* hb = hN + b * (6400 * 256);

    const int pix = pix0 + l15;
    const int oh  = pix / 80, ow = pix % 80;

    float4v acc0 = {0.f, 0.f, 0.f, 0.f};
    float4v acc1 = {0.f, 0.f, 0.f, 0.f};

    for (int tap = 0; tap < 9; tap++){
        const int ih = oh + tap / 3 - 1;
        const int iw = ow + tap % 3 - 1;
        const bool val = ((unsigned)ih < 80u) && ((unsigned)iw < 80u);
        const int sp  = val ? (ih * 80 + iw) : 0;
        const bf16* hp = hb + (size_t)sp * 256 + ksl * 8;
        const bf16* wp = wm + (size_t)tap * 8 * 512 + lane * 8;
        #pragma unroll
        for (int sub = 0; sub < 8; sub++){
            short8 bf_ = {0, 0, 0, 0, 0, 0, 0, 0};
            if (val) bf_ = *reinterpret_cast<const short8*>(hp + sub * 32);
            short8 a0 = *reinterpret_cast<const short8*>(wp + sub * 512);
            short8 a1 = *reinterpret_cast<const short8*>(wp + 72 * 512 + sub * 512);
            acc0 = __builtin_amdgcn_mfma_f32_16x16x32_bf16(a0, bf_, acc0, 0, 0, 0);
            acc1 = __builtin_amdgcn_mfma_f32_16x16x32_bf16(a1, bf_, acc1, 0, 0, 0);
        }
    }

    // C layout: col(pixel) = lane&15, row(oc) = (lane>>4)*4 + r  (+16 for acc1)
    #pragma unroll
    for (int r = 0; r < 4; r++){
        int oc = ksl * 4 + r;
        off[((size_t)b * 18 + oc) * 6400 + pix] = acc0[r] + bias[oc];
    }
    if (ksl == 0){
        #pragma unroll
        for (int r = 0; r < 2; r++){
            int oc = 16 + r;
            off[((size_t)b * 18 + oc) * 6400 + pix] = acc1[r] + bias[oc];
        }
    }
}

// ---------------------------------------------------------------------------
// K3: deform conv MFMA on NHWC h — r15-exact (validated 176.6us): sub-level
// staging with cheap register prefetch, tap-hoisted bilinear state, XCD-
// aligned block mapping.
__global__ __launch_bounds__(256) void k_dconv_nhwc(
    const bf16* __restrict__ hN, const float* __restrict__ off,
    const bf16* __restrict__ wb2,
    const float* __restrict__ g, const float* __restrict__ bb,
    const float* __restrict__ mm, const float* __restrict__ vv,
    float* __restrict__ out)
{
    __shared__ short   A_lds[256 * 40];            // 20,480 B
    __shared__ short   B_lds[64 * 40];             //  5,120 B
    __shared__ ushort4 sidxu[576];                 //  4,608 B
    __shared__ ushort4 swtu [576];                 //  4,608 B
    __shared__ float   sc_s[256], sh_s[256];       //  2,048 B  -> 36,864 B total

    const int tid  = threadIdx.x;
    const int b    = blockIdx.x & 7;               // XCD-aligned (800 = 8*100)
    const int pix0 = (blockIdx.x >> 3) * 64;
    const bf16* hb = hN + b * (6400 * 256);

    {
        float scv = g[tid] * rsqrtf(vv[tid] + EPSBN);
        sc_s[tid] = scv;
        sh_s[tid] = bb[tid] - mm[tid] * scv;
    }

    for (int e = tid; e < 576; e += 256){
        int t = e & 63, k = e >> 6;
        int pix = pix0 + t;
        int oh = pix / 80, ow = pix % 80;
        int kh = k / 3, kw = k % 3;
        float oy = off[(b * 18 + 2 * k    ) * 6400 + pix];
        float ox = off[(b * 18 + 2 * k + 1) * 6400 + pix];
        float py = (float)(oh + kh - 1) + oy;
        float px = (float)(ow + kw - 1) + ox;
        float y0f = floorf(py), x0f = floorf(px);
        float wy1 = py - y0f,  wx1 = px - x0f;
        int y0 = (int)y0f, x0 = (int)x0f;
        unsigned short ii[4], ww[4];
        #pragma unroll
        for (int cy = 0; cy < 2; cy++){
            int   yy = y0 + cy;
            float wy = cy ? wy1 : 1.f - wy1;
            bool  vy = (yy >= 0) && (yy < 80);
            int   yc = min(max(yy, 0), 79);
            #pragma unroll
            for (int cx = 0; cx < 2; cx++){
                int   xx = x0 + cx;
                float wx = cx ? wx1 : 1.f - wx1;
                bool  vx = (xx >= 0) && (xx < 80);
                int   xc = min(max(xx, 0), 79);
                int ci = cy * 2 + cx;
                ii[ci] = (unsigned short)(yc * 80 + xc);
                ww[ci] = f2bf_bits((vy && vx) ? wy * wx : 0.f);
            }
        }
        ushort4 iv; iv.x = ii[0]; iv.y = ii[1]; iv.z = ii[2]; iv.w = ii[3];
        ushort4 wv_; wv_.x = ww[0]; wv_.y = ww[1]; wv_.z = ww[2]; wv_.w = ww[3];
        sidxu[e] = iv;
        swtu [e] = wv_;
    }
    __syncthreads();

    const int t4   = tid >> 2;                     // pixel 0..63
    const int cq   = tid & 3;                      // channel octet (8 contiguous ch in sub)
    const int wv   = tid >> 6;
    const int lane = tid & 63;
    const int lrow = lane & 15;
    const int quad = lane >> 4;
    const int ocA  = tid >> 2;                     // A-stage row base
    const int kqA  = tid & 3;

    const bf16* wA = wb2 + (size_t)ocA * 2304 + kqA * 8;

    float w0, w1, w2, w3;
    const bf16 *p0, *p1, *p2, *p3;
    auto load_tap_state = [&](int tap){
        const int e = tap * 64 + t4;
        ushort4 ipk = sidxu[e];
        ushort4 wpk = swtu[e];
        w0 = bits2f(wpk.x); w1 = bits2f(wpk.y);
        w2 = bits2f(wpk.z); w3 = bits2f(wpk.w);
        p0 = hb + (int)ipk.x * 256 + cq * 8;
        p1 = hb + (int)ipk.y * 256 + cq * 8;
        p2 = hb + (int)ipk.z * 256 + cq * 8;
        p3 = hb + (int)ipk.w * 256 + cq * 8;
    };

    uint4  pa0, pa1, pa2, pa3;                     // A prefetch regs
    short8 pb0, pb1, pb2, pb3;                     // B gather prefetch regs

    auto issue_pref = [&](int kc){
        const bf16* wp = wA + kc * 32;
        pa0 = *reinterpret_cast<const uint4*>(wp);
        pa1 = *reinterpret_cast<const uint4*>(wp + (size_t)64 * 2304);
        pa2 = *reinterpret_cast<const uint4*>(wp + (size_t)128 * 2304);
        pa3 = *reinterpret_cast<const uint4*>(wp + (size_t)192 * 2304);
        const int co = (kc & 7) * 32;
        pb0 = *reinterpret_cast<const short8*>(p0 + co);
        pb1 = *reinterpret_cast<const short8*>(p1 + co);
        pb2 = *reinterpret_cast<const short8*>(p2 + co);
        pb3 = *reinterpret_cast<const short8*>(p3 + co);
    };

    float4v acc[4][4];
    #pragma unroll
    for (int i = 0; i < 4; i++)
        #pragma unroll
        for (int j = 0; j < 4; j++)
            acc[i][j] = (float4v){0.f, 0.f, 0.f, 0.f};

    load_tap_state(0);
    issue_pref(0);

    for (int tap = 0; tap < 9; tap++){
        for (int sub = 0; sub < 8; sub++){
            const int kc = tap * 8 + sub;

            // blend for kc (waits pb vmcnt — issued one MFMA block ago)
            short8 ob;
            #pragma unroll
            for (int el = 0; el < 8; el++){
                float f = w0 * bits2f((unsigned short)pb0[el])
                        + w1 * bits2f((unsigned short)pb1[el])
                        + w2 * bits2f((unsigned short)pb2[el])
                        + w3 * bits2f((unsigned short)pb3[el]);
                ob[el] = (short)f2bf_bits(f);
            }

            __syncthreads();                       // prev iter's ds_reads done

            // stage kc
            *reinterpret_cast<uint4*>(&A_lds[(0 * 64 + ocA) * 40 + kqA * 8]) = pa0;
            *reinterpret_cast<uint4*>(&A_lds[(1 * 64 + ocA) * 40 + kqA * 8]) = pa1;
            *reinterpret_cast<uint4*>(&A_lds[(2 * 64 + ocA) * 40 + kqA * 8]) = pa2;
            *reinterpret_cast<uint4*>(&A_lds[(3 * 64 + ocA) * 40 + kqA * 8]) = pa3;
            *reinterpret_cast<short8*>(&B_lds[t4 * 40 + cq * 8]) = ob;

            __syncthreads();                       // kc staged

            // prefetch kc+1 (cheap: imm offsets; new tap state once per 8)
            if (kc < 71){
                if (sub == 7) load_tap_state(tap + 1);
                issue_pref(kc + 1);
            }

            // MFMA for kc — covers the just-issued loads
            short8 af[4], bfv[4];
            #pragma unroll
            for (int i = 0; i < 4; i++){
                int row = wv * 64 + i * 16 + lrow;
                af[i] = *reinterpret_cast<const short8*>(&A_lds[row * 40 + quad * 8]);
            }
            #pragma unroll
            for (int j = 0; j < 4; j++){
                bfv[j] = *reinterpret_cast<const short8*>(&B_lds[(j * 16 + lrow) * 40 + quad * 8]);
            }
            #pragma unroll
            for (int i = 0; i < 4; i++)
                #pragma unroll
                for (int j = 0; j < 4; j++)
                    acc[i][j] = __builtin_amdgcn_mfma_f32_16x16x32_bf16(af[i], bfv[j], acc[i][j], 0, 0, 0);
        }
    }

    #pragma unroll
    for (int i = 0; i < 4; i++){
        #pragma unroll
        for (int r = 0; r < 4; r++){
            int oc = wv * 64 + i * 16 + quad * 4 + r;
            float scv = sc_s[oc], shv = sh_s[oc];
            #pragma unroll
            for (int j = 0; j < 4; j++){
                int pix = pix0 + j * 16 + lrow;
                out[(b * 256 + oc) * 6400 + pix] = silu_(acc[i][j][r] * scv + shv);
            }
        }
    }
}

// ---------------------------------------------------------------------------
extern "C" void kernel_launch(void* const* d_in, const int* in_sizes, int n_in,
                              void* d_out, int out_size, void* d_ws, size_t ws_size,
                              hipStream_t stream)
{
    (void)in_sizes; (void)n_in; (void)out_size;

    const float* x  = (const float*)d_in[0];
    const float* w1 = (const float*)d_in[1];
    const float* g1 = (const float*)d_in[2];
    const float* b1 = (const float*)d_in[3];
    const float* m1 = (const float*)d_in[4];
    const float* v1 = (const float*)d_in[5];
    const float* wo = (const float*)d_in[6];
    const float* bo = (const float*)d_in[7];
    const float* wd = (const float*)d_in[8];
    const float* g2 = (const float*)d_in[9];
    const float* b2 = (const float*)d_in[10];
    const float* m2 = (const float*)d_in[11];
    const float* v2 = (const float*)d_in[12];
    float* outp = (float*)d_out;

    char*  wsb  = (char*)d_ws;
    bf16*  hNb  = (bf16*) wsb;                      // 26,214,400 B
    float* obuf = (float*)(wsb + 26214400);         //  3,686,400 B
    bf16*  wb2b = (bf16*) (wsb + 29900800);         //  1,179,648 B
    bf16*  wbb  = (bf16*) (wsb + 31080448);         //    589,824 B
    bf16*  wmof = (bf16*) (wsb + 31670272);         //    147,456 B (<= 165,888 slot)
    bf16*  xNb  = (bf16*) (wsb + 31836160);         // 52,428,800 B

    const size_t need_primary = 84264960;

    hipLaunchKernelGGL(k_wdprep,  dim3(2304), dim3(256), 0, stream, wd, wb2b);
    hipLaunchKernelGGL(k_woprepm, dim3(288),  dim3(256), 0, stream, wo, wmof);

    if (ws_size >= need_primary){
        hipLaunchKernelGGL(k_wprep1t, dim3(1152), dim3(256), 0, stream, w1, wbb);
        hipLaunchKernelGGL(k_xprep,   dim3(3200), dim3(256), 0, stream, x, xNb);
        hipLaunchKernelGGL(k_conv1n,  dim3(800),  dim3(256), 0, stream, xNb, wbb, g1, b1, m1, v1, hNb);
    } else {
        hipLaunchKernelGGL(k_wprep,   dim3(1152), dim3(256), 0, stream, w1, wbb);
        hipLaunchKernelGGL(k_conv1,   dim3(800),  dim3(256), 0, stream, x, wbb, g1, b1, m1, v1, hNb);
    }

    hipLaunchKernelGGL(k_off_m,     dim3(800), dim3(256), 0, stream, hNb, wmof, bo, obuf);
    hipLaunchKernelGGL(k_dconv_nhwc,dim3(800), dim3(256), 0, stream, hNb, obuf, wb2b, g2, b2, m2, v2, outp);
}

// Round 14
// 457.782 us; speedup vs baseline: 1.2709x; 1.0374x over previous
//
#include <hip/hip_runtime.h>
#include <hip/hip_bf16.h>

// DCNConv pipeline, MI355X round 19: conv1n N-tile 64 -> 128 pixels
// (m93-family tile increase on the validated 2-barrier structure; halves
// total barrier events 36x800 -> 36x400, 32 MFMA/iter/wave, acc[4][8]
// ~220 regs < 256 spill cliff). Everything else r18-exact (474.9us best:
// dconv r15 176.6us, off_m barrier-free MFMA, XCD swizzles).
//
// Primary ws layout (84,264,960 B):
//   [0)          hN    bf16 [8][6400pix][256c] = 26,214,400 B
//   [26,214,400) off   fp32 [8][18][6400]      =  3,686,400 B
//   [29,900,800) wb2   bf16 [256][2304]        =  1,179,648 B (dconv w, tap-major)
//   [31,080,448) wb1   bf16 [256][1152]        =    589,824 B (conv1 w)
//   [31,670,272) wToffm bf16 [2][72][512]      =    147,456 B (off w, MFMA-fragment-major)
//   [31,836,160) xN    bf16 [8][25600pix][128c]= 52,428,800 B

typedef __hip_bfloat16 bf16;
typedef __attribute__((ext_vector_type(8))) short short8;
typedef __attribute__((ext_vector_type(4))) float float4v;

#define EPSBN 1e-5f

__device__ __forceinline__ float bf2f(bf16 x){ return __bfloat162float(x); }
__device__ __forceinline__ float bits2f(unsigned short u){ return __uint_as_float(((unsigned)u) << 16); }
__device__ __forceinline__ float silu_(float x){ return x / (1.f + __expf(-x)); }
__device__ __forceinline__ unsigned short f2bf_bits(float f){
    union { float f; unsigned u; } uf; uf.f = f;
    unsigned r = uf.u + 0x7fff + ((uf.u >> 16) & 1);   // RNE (finite inputs)
    return (unsigned short)(r >> 16);
}

// ---------------------------------------------------------------------------
// K0a: dconv_w [256oc][256c][9tap] fp32 -> wb2 bf16 [256oc][2304], kk = tap*256+c.
__global__ __launch_bounds__(256) void k_wdprep(const float* __restrict__ w, bf16* __restrict__ wb2)
{
    int idx = blockIdx.x * 256 + threadIdx.x;
    if (idx >= 256 * 2304) return;
    int oc  = idx / 2304;
    int r   = idx - oc * 2304;
    int tap = r >> 8;
    int c   = r & 255;
    wb2[idx] = __float2bfloat16(w[(oc * 256 + c) * 9 + tap]);
}

// K0b (primary): conv1 weights -> bf16 TAP-MAJOR [oc][tap*128+c].
__global__ __launch_bounds__(256) void k_wprep1t(const float* __restrict__ w, bf16* __restrict__ wb)
{
    int idx = blockIdx.x * 256 + threadIdx.x;      // 294,912
    if (idx >= 256 * 1152) return;
    int oc  = idx / 1152;
    int r   = idx - oc * 1152;
    int tap = r >> 7;
    int c   = r & 127;
    wb[idx] = __float2bfloat16(w[(oc * 128 + c) * 9 + tap]);
}

// K0b' (fallback): conv1 weights -> bf16, c-major [oc][c*9+tap] (round-6).
__global__ __launch_bounds__(256) void k_wprep(const float* __restrict__ w, bf16* __restrict__ wb)
{
    int idx = blockIdx.x * 256 + threadIdx.x;
    if (idx >= 256 * 1152) return;
    wb[idx] = __float2bfloat16(w[idx]);
}

// K0c: off_w [18oc][256c][9tap] fp32 -> wToffm bf16 MFMA-FRAGMENT-MAJOR (r18).
__global__ __launch_bounds__(256) void k_woprepm(const float* __restrict__ w, bf16* __restrict__ wm)
{
    int idx = blockIdx.x * 256 + threadIdx.x;      // 73,728
    if (idx >= 2 * 72 * 512) return;
    int j    = idx & 7;
    int lane = (idx >> 3) & 63;
    int frag = idx >> 9;                           // 0..143
    int half = frag / 72;
    int kc   = frag - half * 72;
    int oc   = half * 16 + (lane & 15);
    int kk   = kc * 32 + (lane >> 4) * 8 + j;
    int tap  = kk >> 8;
    int c    = kk & 255;
    float v  = (oc < 18) ? w[(oc * 256 + c) * 9 + tap] : 0.f;
    wm[idx] = __float2bfloat16(v);
}

// K0d: x NCHW fp32 -> xN NHWC bf16 via LDS tile transpose.
__global__ __launch_bounds__(256) void k_xprep(const float* __restrict__ x, bf16* __restrict__ xN)
{
    __shared__ short sm[64 * 132];                 // 16,896 B
    const int tid  = threadIdx.x;
    const int b    = blockIdx.x / 400;             // 3200 blocks
    const int pix0 = (blockIdx.x % 400) * 64;
    const int lane = tid & 63;
    const int wq   = tid >> 6;
    const float* xb = x + (size_t)b * 128 * 25600;

    #pragma unroll
    for (int i = 0; i < 32; i++){
        int c = i * 4 + wq;
        sm[lane * 132 + c] = (short)f2bf_bits(xb[c * 25600 + pix0 + lane]);
    }
    __syncthreads();

    bf16* xo = xN + ((size_t)b * 25600 + pix0) * 128;
    #pragma unroll
    for (int j = 0; j < 8; j++){
        int idx = j * 256 + tid;                   // 0..2047
        int p = idx >> 5, q = idx & 31;
        *reinterpret_cast<ushort4*>(xo + p * 128 + q * 4) =
            *reinterpret_cast<const ushort4*>(&sm[p * 132 + q * 4]);
    }
}

// ---------------------------------------------------------------------------
// K1 (primary): conv1 (3x3 s2 p1) + BN1 + SiLU, MFMA implicit GEMM on NHWC xN.
// Round-19: 128-pixel N-tile (400 blocks), register-prefetch pipeline, XCD
// swizzle. Per iter: 32 MFMA/wave (acc[4][8]); B-stage = 2 masked 16B loads.
__global__ __launch_bounds__(256) void k_conv1n(
    const bf16* __restrict__ xN, const bf16* __restrict__ wb,
    const float* __restrict__ g, const float* __restrict__ bb,
    const float* __restrict__ mm, const float* __restrict__ vv,
    bf16* __restrict__ hN)
{
    __shared__ short A_lds[256 * 40];              // 20,480 B
    __shared__ short B_lds[128 * 40];              // 10,240 B
    __shared__ unsigned short nidx[1152];          //  2,304 B
    __shared__ unsigned short nmsk[1152];          //  2,304 B
    __shared__ float sc_s[256], sh_s[256];         //  2,048 B  -> 37,376 B

    const int tid  = threadIdx.x;
    const int b    = blockIdx.x & 7;               // XCD-aligned (400 = 8*50)
    const int pix0 = (blockIdx.x >> 3) * 128;
    const bf16* xb = xN + (size_t)b * 25600 * 128;

    {
        float scv = g[tid] * rsqrtf(vv[tid] + EPSBN);
        sc_s[tid] = scv;
        sh_s[tid] = bb[tid] - mm[tid] * scv;
    }

    for (int e = tid; e < 1152; e += 256){
        int t = e & 127, k = e >> 7;
        int pix = pix0 + t;
        int oh = pix / 80, ow = pix % 80;
        int ih = 2 * oh + k / 3 - 1;
        int iw = 2 * ow + k % 3 - 1;
        nmsk[e] = ((ih | iw) >= 0) ? 1 : 0;
        nidx[e] = (unsigned short)(max(ih, 0) * 160 + max(iw, 0));
    }
    __syncthreads();

    const int t4   = tid >> 2;                     // pixel slot 0..63 (pixels t4, t4+64)
    const int cq   = tid & 3;                      // channel octet
    const int wv   = tid >> 6;
    const int lane = tid & 63;
    const int lrow = lane & 15;
    const int quad = lane >> 4;
    const int ocA  = tid >> 2;                     // A-stage row
    const int kqA  = tid & 3;

    uint4  pa0, pa1, pa2, pa3;                     // A prefetch regs
    short8 pb0, pb1;                               // B prefetch regs (2 pixels)

    float4v acc[4][8];
    #pragma unroll
    for (int i = 0; i < 4; i++)
        #pragma unroll
        for (int j = 0; j < 8; j++)
            acc[i][j] = (float4v){0.f, 0.f, 0.f, 0.f};

    auto issue_pref = [&](int kc){
        const bf16* wp = wb + kc * 32 + kqA * 8;
        pa0 = *reinterpret_cast<const uint4*>(wp + (0 * 64 + ocA) * 1152);
        pa1 = *reinterpret_cast<const uint4*>(wp + (1 * 64 + ocA) * 1152);
        pa2 = *reinterpret_cast<const uint4*>(wp + (2 * 64 + ocA) * 1152);
        pa3 = *reinterpret_cast<const uint4*>(wp + (3 * 64 + ocA) * 1152);
        const int tap = kc >> 2;
        const int cb  = (kc & 3) * 32 + cq * 8;
        #pragma unroll
        for (int s = 0; s < 2; s++){
            const int e  = tap * 128 + t4 + s * 64;
            const int sp = (int)nidx[e];
            const bool mv = nmsk[e] != 0;
            short8 v = {0, 0, 0, 0, 0, 0, 0, 0};
            if (mv) v = *reinterpret_cast<const short8*>(xb + (size_t)sp * 128 + cb);
            if (s == 0) pb0 = v; else pb1 = v;
        }
    };
    auto write_stage = [&](){
        *reinterpret_cast<uint4*>(&A_lds[(0 * 64 + ocA) * 40 + kqA * 8]) = pa0;
        *reinterpret_cast<uint4*>(&A_lds[(1 * 64 + ocA) * 40 + kqA * 8]) = pa1;
        *reinterpret_cast<uint4*>(&A_lds[(2 * 64 + ocA) * 40 + kqA * 8]) = pa2;
        *reinterpret_cast<uint4*>(&A_lds[(3 * 64 + ocA) * 40 + kqA * 8]) = pa3;
        *reinterpret_cast<short8*>(&B_lds[(t4     ) * 40 + cq * 8]) = pb0;
        *reinterpret_cast<short8*>(&B_lds[(t4 + 64) * 40 + cq * 8]) = pb1;
    };

    issue_pref(0);
    write_stage();
    __syncthreads();

    for (int kc = 0; kc < 36; kc++){
        if (kc < 35) issue_pref(kc + 1);           // in-flight across the MFMA block

        short8 af[4];
        #pragma unroll
        for (int i = 0; i < 4; i++){
            int row = wv * 64 + i * 16 + lrow;
            af[i] = *reinterpret_cast<const short8*>(&A_lds[row * 40 + quad * 8]);
        }
        #pragma unroll
        for (int j = 0; j < 8; j++){
            short8 bfv = *reinterpret_cast<const short8*>(&B_lds[(j * 16 + lrow) * 40 + quad * 8]);
            #pragma unroll
            for (int i = 0; i < 4; i++)
                acc[i][j] = __builtin_amdgcn_mfma_f32_16x16x32_bf16(af[i], bfv, acc[i][j], 0, 0, 0);
        }

        if (kc < 35){
            __syncthreads();                       // all reads of kc done
            write_stage();                         // stage kc+1
            __syncthreads();                       // kc+1 ready
        }
    }

    #pragma unroll
    for (int i = 0; i < 4; i++){
        int oc0 = wv * 64 + i * 16 + quad * 4;
        float s0 = sc_s[oc0+0], h0 = sh_s[oc0+0];
        float s1 = sc_s[oc0+1], h1 = sh_s[oc0+1];
        float s2 = sc_s[oc0+2], h2 = sh_s[oc0+2];
        float s3 = sc_s[oc0+3], h3 = sh_s[oc0+3];
        #pragma unroll
        for (int j = 0; j < 8; j++){
            int pix = pix0 + j * 16 + lrow;
            ushort4 o;
            o.x = f2bf_bits(silu_(acc[i][j][0] * s0 + h0));
            o.y = f2bf_bits(silu_(acc[i][j][1] * s1 + h1));
            o.z = f2bf_bits(silu_(acc[i][j][2] * s2 + h2));
            o.w = f2bf_bits(silu_(acc[i][j][3] * s3 + h3));
            *reinterpret_cast<ushort4*>(hN + ((size_t)b * 6400 + pix) * 256 + oc0) = o;
        }
    }
}

// K1 (fallback): round-6 conv1 on NCHW fp32 x (validated), verbatim.
__global__ __launch_bounds__(256) void k_conv1(
    const float* __restrict__ x, const bf16* __restrict__ wb,
    const float* __restrict__ g, const float* __restrict__ bb,
    const float* __restrict__ mm, const float* __restrict__ vv,
    bf16* __restrict__ hN)
{
    __shared__ short A_lds[256 * 40];
    __shared__ short B_lds[64 * 40];
    __shared__ float sc_s[256], sh_s[256];

    const int tid  = threadIdx.x;
    const int b    = blockIdx.x / 100;
    const int pix0 = (blockIdx.x % 100) * 64;
    const float* xb = x + b * (128 * 25600);

    {
        float scv = g[tid] * rsqrtf(vv[tid] + EPSBN);
        sc_s[tid] = scv;
        sh_s[tid] = bb[tid] - mm[tid] * scv;
    }

    const int k_in = tid & 31;
    const int prow = tid >> 5;
    int oh8[8], ow8[8];
    #pragma unroll
    for (int p = 0; p < 8; p++){
        int pix = pix0 + prow + p * 8;
        oh8[p] = pix / 80; ow8[p] = pix % 80;
    }

    const int wv   = tid >> 6;
    const int lane = tid & 63;
    const int lrow = lane & 15;
    const int quad = lane >> 4;

    float4v acc[4][4];
    #pragma unroll
    for (int i = 0; i < 4; i++)
        #pragma unroll
        for (int j = 0; j < 4; j++)
            acc[i][j] = (float4v){0.f, 0.f, 0.f, 0.f};

    for (int kc = 0; kc < 36; kc++){
        const int k0 = kc * 32;
        __syncthreads();

        #pragma unroll
        for (int p2 = 0; p2 < 4; p2++){
            int idx = p2 * 256 + tid;
            int oc  = idx >> 2;
            int kq  = idx & 3;
            *reinterpret_cast<uint4*>(&A_lds[oc * 40 + kq * 8]) =
                *reinterpret_cast<const uint4*>(wb + oc * 1152 + k0 + kq * 8);
        }

        {
            int kk  = k0 + k_in;
            int c   = kk / 9;
            int tap = kk - 9 * c;
            int kh  = tap / 3 - 1;
            int kw  = tap - 3 * (tap / 3) - 1;
            const float* xc = xb + c * 25600;
            #pragma unroll
            for (int p = 0; p < 8; p++){
                int ih = 2 * oh8[p] + kh;
                int iw = 2 * ow8[p] + kw;
                float v = 0.f;
                if ((ih | iw) >= 0) v = xc[ih * 160 + iw];
                B_lds[(prow + p * 8) * 40 + k_in] = (short)f2bf_bits(v);
            }
        }
        __syncthreads();

        short8 af[4], bfv[4];
        #pragma unroll
        for (int i = 0; i < 4; i++){
            int row = wv * 64 + i * 16 + lrow;
            af[i] = *reinterpret_cast<const short8*>(&A_lds[row * 40 + quad * 8]);
        }
        #pragma unroll
        for (int j = 0; j < 4; j++){
            bfv[j] = *reinterpret_cast<const short8*>(&B_lds[(j * 16 + lrow) * 40 + quad * 8]);
        }
        #pragma unroll
        for (int i = 0; i < 4; i++)
            #pragma unroll
            for (int j = 0; j < 4; j++)
                acc[i][j] = __builtin_amdgcn_mfma_f32_16x16x32_bf16(af[i], bfv[j], acc[i][j], 0, 0, 0);
    }

    #pragma unroll
    for (int i = 0; i < 4; i++){
        int oc0 = wv * 64 + i * 16 + quad * 4;
        float s0 = sc_s[oc0+0], h0 = sh_s[oc0+0];
        float s1 = sc_s[oc0+1], h1 = sh_s[oc0+1];
        float s2 = sc_s[oc0+2], h2 = sh_s[oc0+2];
        float s3 = sc_s[oc0+3], h3 = sh_s[oc0+3];
        #pragma unroll
        for (int j = 0; j < 4; j++){
            int pix = pix0 + j * 16 + lrow;
            ushort4 o;
            o.x = f2bf_bits(silu_(acc[i][j][0] * s0 + h0));
            o.y = f2bf_bits(silu_(acc[i][j][1] * s1 + h1));
            o.z = f2bf_bits(silu_(acc[i][j][2] * s2 + h2));
            o.w = f2bf_bits(silu_(acc[i][j][3] * s3 + h3));
            *reinterpret_cast<ushort4*>(hN + (b * 6400 + pix) * 256 + oc0) = o;
        }
    }
}

// ---------------------------------------------------------------------------
// K2: offset conv as barrier-free MFMA (r18, validated). Per wave: 16 pixels
// x 18 oc (padded 32), 72 K-chunks, no LDS, no barriers.
__global__ __launch_bounds__(256) void k_off_m(
    const bf16* __restrict__ hN, const bf16* __restrict__ wm,
    const float* __restrict__ bias, float* __restrict__ off)
{
    const int tid  = threadIdx.x;
    const int b    = blockIdx.x & 7;               // XCD-aligned (800 = 8*100)
    const int pix0 = (blockIdx.x >> 3) * 64 + (tid >> 6) * 16;  // wave's 16 pixels
    const int lane = tid & 63;
    const int l15  = lane & 15;
    const int ksl  = lane >> 4;
    const bf16* hb = hN + b * (6400 * 256);

    const int pix = pix0 + l15;
    const int oh  = pix / 80, ow = pix % 80;

    float4v acc0 = {0.f, 0.f, 0.f, 0.f};
    float4v acc1 = {0.f, 0.f, 0.f, 0.f};

    for (int tap = 0; tap < 9; tap++){
        const int ih = oh + tap / 3 - 1;
        const int iw = ow + tap % 3 - 1;
        const bool val = ((unsigned)ih < 80u) && ((unsigned)iw < 80u);
        const int sp  = val ? (ih * 80 + iw) : 0;
        const bf16* hp = hb + (size_t)sp * 256 + ksl * 8;
        const bf16* wp = wm + (size_t)tap * 8 * 512 + lane * 8;
        #pragma unroll
        for (int sub = 0; sub < 8; sub++){
            short8 bf_ = {0, 0, 0, 0, 0, 0, 0, 0};
            if (val) bf_ = *reinterpret_cast<const short8*>(hp + sub * 32);
            short8 a0 = *reinterpret_cast<const short8*>(wp + sub * 512);
            short8 a1 = *reinterpret_cast<const short8*>(wp + 72 * 512 + sub * 512);
            acc0 = __builtin_amdgcn_mfma_f32_16x16x32_bf16(a0, bf_, acc0, 0, 0, 0);
            acc1 = __builtin_amdgcn_mfma_f32_16x16x32_bf16(a1, bf_, acc1, 0, 0, 0);
        }
    }

    // C layout: col(pixel) = lane&15, row(oc) = (lane>>4)*4 + r  (+16 for acc1)
    #pragma unroll
    for (int r = 0; r < 4; r++){
        int oc = ksl * 4 + r;
        off[((size_t)b * 18 + oc) * 6400 + pix] = acc0[r] + bias[oc];
    }
    if (ksl == 0){
        #pragma unroll
        for (int r = 0; r < 2; r++){
            int oc = 16 + r;
            off[((size_t)b * 18 + oc) * 6400 + pix] = acc1[r] + bias[oc];
        }
    }
}

// ---------------------------------------------------------------------------
// K3: deform conv MFMA on NHWC h — r15-exact (validated 176.6us).
__global__ __launch_bounds__(256) void k_dconv_nhwc(
    const bf16* __restrict__ hN, const float* __restrict__ off,
    const bf16* __restrict__ wb2,
    const float* __restrict__ g, const float* __restrict__ bb,
    const float* __restrict__ mm, const float* __restrict__ vv,
    float* __restrict__ out)
{
    __shared__ short   A_lds[256 * 40];            // 20,480 B
    __shared__ short   B_lds[64 * 40];             //  5,120 B
    __shared__ ushort4 sidxu[576];                 //  4,608 B
    __shared__ ushort4 swtu [576];                 //  4,608 B
    __shared__ float   sc_s[256], sh_s[256];       //  2,048 B  -> 36,864 B total

    const int tid  = threadIdx.x;
    const int b    = blockIdx.x & 7;               // XCD-aligned (800 = 8*100)
    const int pix0 = (blockIdx.x >> 3) * 64;
    const bf16* hb = hN + b * (6400 * 256);

    {
        float scv = g[tid] * rsqrtf(vv[tid] + EPSBN);
        sc_s[tid] = scv;
        sh_s[tid] = bb[tid] - mm[tid] * scv;
    }

    for (int e = tid; e < 576; e += 256){
        int t = e & 63, k = e >> 6;
        int pix = pix0 + t;
        int oh = pix / 80, ow = pix % 80;
        int kh = k / 3, kw = k % 3;
        float oy = off[(b * 18 + 2 * k    ) * 6400 + pix];
        float ox = off[(b * 18 + 2 * k + 1) * 6400 + pix];
        float py = (float)(oh + kh - 1) + oy;
        float px = (float)(ow + kw - 1) + ox;
        float y0f = floorf(py), x0f = floorf(px);
        float wy1 = py - y0f,  wx1 = px - x0f;
        int y0 = (int)y0f, x0 = (int)x0f;
        unsigned short ii[4], ww[4];
        #pragma unroll
        for (int cy = 0; cy < 2; cy++){
            int   yy = y0 + cy;
            float wy = cy ? wy1 : 1.f - wy1;
            bool  vy = (yy >= 0) && (yy < 80);
            int   yc = min(max(yy, 0), 79);
            #pragma unroll
            for (int cx = 0; cx < 2; cx++){
                int   xx = x0 + cx;
                float wx = cx ? wx1 : 1.f - wx1;
                bool  vx = (xx >= 0) && (xx < 80);
                int   xc = min(max(xx, 0), 79);
                int ci = cy * 2 + cx;
                ii[ci] = (unsigned short)(yc * 80 + xc);
                ww[ci] = f2bf_bits((vy && vx) ? wy * wx : 0.f);
            }
        }
        ushort4 iv; iv.x = ii[0]; iv.y = ii[1]; iv.z = ii[2]; iv.w = ii[3];
        ushort4 wv_; wv_.x = ww[0]; wv_.y = ww[1]; wv_.z = ww[2]; wv_.w = ww[3];
        sidxu[e] = iv;
        swtu [e] = wv_;
    }
    __syncthreads();

    const int t4   = tid >> 2;                     // pixel 0..63
    const int cq   = tid & 3;                      // channel octet (8 contiguous ch in sub)
    const int wv   = tid >> 6;
    const int lane = tid & 63;
    const int lrow = lane & 15;
    const int quad = lane >> 4;
    const int ocA  = tid >> 2;                     // A-stage row base
    const int kqA  = tid & 3;

    const bf16* wA = wb2 + (size_t)ocA * 2304 + kqA * 8;

    float w0, w1, w2, w3;
    const bf16 *p0, *p1, *p2, *p3;
    auto load_tap_state = [&](int tap){
        const int e = tap * 64 + t4;
        ushort4 ipk = sidxu[e];
        ushort4 wpk = swtu[e];
        w0 = bits2f(wpk.x); w1 = bits2f(wpk.y);
        w2 = bits2f(wpk.z); w3 = bits2f(wpk.w);
        p0 = hb + (int)ipk.x * 256 + cq * 8;
        p1 = hb + (int)ipk.y * 256 + cq * 8;
        p2 = hb + (int)ipk.z * 256 + cq * 8;
        p3 = hb + (int)ipk.w * 256 + cq * 8;
    };

    uint4  pa0, pa1, pa2, pa3;                     // A prefetch regs
    short8 pb0, pb1, pb2, pb3;                     // B gather prefetch regs

    auto issue_pref = [&](int kc){
        const bf16* wp = wA + kc * 32;
        pa0 = *reinterpret_cast<const uint4*>(wp);
        pa1 = *reinterpret_cast<const uint4*>(wp + (size_t)64 * 2304);
        pa2 = *reinterpret_cast<const uint4*>(wp + (size_t)128 * 2304);
        pa3 = *reinterpret_cast<const uint4*>(wp + (size_t)192 * 2304);
        const int co = (kc & 7) * 32;
        pb0 = *reinterpret_cast<const short8*>(p0 + co);
        pb1 = *reinterpret_cast<const short8*>(p1 + co);
        pb2 = *reinterpret_cast<const short8*>(p2 + co);
        pb3 = *reinterpret_cast<const short8*>(p3 + co);
    };

    float4v acc[4][4];
    #pragma unroll
    for (int i = 0; i < 4; i++)
        #pragma unroll
        for (int j = 0; j < 4; j++)
            acc[i][j] = (float4v){0.f, 0.f, 0.f, 0.f};

    load_tap_state(0);
    issue_pref(0);

    for (int tap = 0; tap < 9; tap++){
        for (int sub = 0; sub < 8; sub++){
            const int kc = tap * 8 + sub;

            // blend for kc (waits pb vmcnt — issued one MFMA block ago)
            short8 ob;
            #pragma unroll
            for (int el = 0; el < 8; el++){
                float f = w0 * bits2f((unsigned short)pb0[el])
                        + w1 * bits2f((unsigned short)pb1[el])
                        + w2 * bits2f((unsigned short)pb2[el])
                        + w3 * bits2f((unsigned short)pb3[el]);
                ob[el] = (short)f2bf_bits(f);
            }

            __syncthreads();                       // prev iter's ds_reads done

            // stage kc
            *reinterpret_cast<uint4*>(&A_lds[(0 * 64 + ocA) * 40 + kqA * 8]) = pa0;
            *reinterpret_cast<uint4*>(&A_lds[(1 * 64 + ocA) * 40 + kqA * 8]) = pa1;
            *reinterpret_cast<uint4*>(&A_lds[(2 * 64 + ocA) * 40 + kqA * 8]) = pa2;
            *reinterpret_cast<uint4*>(&A_lds[(3 * 64 + ocA) * 40 + kqA * 8]) = pa3;
            *reinterpret_cast<short8*>(&B_lds[t4 * 40 + cq * 8]) = ob;

            __syncthreads();                       // kc staged

            // prefetch kc+1 (cheap: imm offsets; new tap state once per 8)
            if (kc < 71){
                if (sub == 7) load_tap_state(tap + 1);
                issue_pref(kc + 1);
            }

            // MFMA for kc — covers the just-issued loads
            short8 af[4], bfv[4];
            #pragma unroll
            for (int i = 0; i < 4; i++){
                int row = wv * 64 + i * 16 + lrow;
                af[i] = *reinterpret_cast<const short8*>(&A_lds[row * 40 + quad * 8]);
            }
            #pragma unroll
            for (int j = 0; j < 4; j++){
                bfv[j] = *reinterpret_cast<const short8*>(&B_lds[(j * 16 + lrow) * 40 + quad * 8]);
            }
            #pragma unroll
            for (int i = 0; i < 4; i++)
                #pragma unroll
                for (int j = 0; j < 4; j++)
                    acc[i][j] = __builtin_amdgcn_mfma_f32_16x16x32_bf16(af[i], bfv[j], acc[i][j], 0, 0, 0);
        }
    }

    #pragma unroll
    for (int i = 0; i < 4; i++){
        #pragma unroll
        for (int r = 0; r < 4; r++){
            int oc = wv * 64 + i * 16 + quad * 4 + r;
            float scv = sc_s[oc], shv = sh_s[oc];
            #pragma unroll
            for (int j = 0; j < 4; j++){
                int pix = pix0 + j * 16 + lrow;
                out[(b * 256 + oc) * 6400 + pix] = silu_(acc[i][j][r] * scv + shv);
            }
        }
    }
}

// ---------------------------------------------------------------------------
extern "C" void kernel_launch(void* const* d_in, const int* in_sizes, int n_in,
                              void* d_out, int out_size, void* d_ws, size_t ws_size,
                              hipStream_t stream)
{
    (void)in_sizes; (void)n_in; (void)out_size;

    const float* x  = (const float*)d_in[0];
    const float* w1 = (const float*)d_in[1];
    const float* g1 = (const float*)d_in[2];
    const float* b1 = (const float*)d_in[3];
    const float* m1 = (const float*)d_in[4];
    const float* v1 = (const float*)d_in[5];
    const float* wo = (const float*)d_in[6];
    const float* bo = (const float*)d_in[7];
    const float* wd = (const float*)d_in[8];
    const float* g2 = (const float*)d_in[9];
    const float* b2 = (const float*)d_in[10];
    const float* m2 = (const float*)d_in[11];
    const float* v2 = (const float*)d_in[12];
    float* outp = (float*)d_out;

    char*  wsb  = (char*)d_ws;
    bf16*  hNb  = (bf16*) wsb;                      // 26,214,400 B
    float* obuf = (float*)(wsb + 26214400);         //  3,686,400 B
    bf16*  wb2b = (bf16*) (wsb + 29900800);         //  1,179,648 B
    bf16*  wbb  = (bf16*) (wsb + 31080448);         //    589,824 B
    bf16*  wmof = (bf16*) (wsb + 31670272);         //    147,456 B (<= 165,888 slot)
    bf16*  xNb  = (bf16*) (wsb + 31836160);         // 52,428,800 B

    const size_t need_primary = 84264960;

    hipLaunchKernelGGL(k_wdprep,  dim3(2304), dim3(256), 0, stream, wd, wb2b);
    hipLaunchKernelGGL(k_woprepm, dim3(288),  dim3(256), 0, stream, wo, wmof);

    if (ws_size >= need_primary){
        hipLaunchKernelGGL(k_wprep1t, dim3(1152), dim3(256), 0, stream, w1, wbb);
        hipLaunchKernelGGL(k_xprep,   dim3(3200), dim3(256), 0, stream, x, xNb);
        hipLaunchKernelGGL(k_conv1n,  dim3(400),  dim3(256), 0, stream, xNb, wbb, g1, b1, m1, v1, hNb);
    } else {
        hipLaunchKernelGGL(k_wprep,   dim3(1152), dim3(256), 0, stream, w1, wbb);
        hipLaunchKernelGGL(k_conv1,   dim3(800),  dim3(256), 0, stream, x, wbb, g1, b1, m1, v1, hNb);
    }

    hipLaunchKernelGGL(k_off_m,     dim3(800), dim3(256), 0, stream, hNb, wmof, bo, obuf);
    hipLaunchKernelGGL(k_dconv_nhwc,dim3(800), dim3(256), 0, stream, hNb, obuf, wb2b, g2, b2, m2, v2, outp);
}

// Round 15
// 449.886 us; speedup vs baseline: 1.2932x; 1.0176x over previous
//
#include <hip/hip_runtime.h>
#include <hip/hip_bf16.h>

// DCNConv pipeline, MI355X round 20: off_m aspect-ratio fix. r18-delta
// arithmetic shows off_m ~64us, dominated by A-fragment L2 re-reads
// (16 pix/wave -> 921MB L2 traffic for a 144KB operand). This round:
// 32 pixels/wave (400 blocks, 2 B-frags per A-pair, 4 MFMA/A-load),
// halving A-traffic to 460MB while keeping 6.25 waves/CU (no barriers).
// Everything else r19-exact (457.8us best: dconv r15 175.7us, conv1n
// 128-pix tile, XCD swizzles).
//
// Primary ws layout (84,264,960 B):
//   [0)          hN    bf16 [8][6400pix][256c] = 26,214,400 B
//   [26,214,400) off   fp32 [8][18][6400]      =  3,686,400 B
//   [29,900,800) wb2   bf16 [256][2304]        =  1,179,648 B (dconv w, tap-major)
//   [31,080,448) wb1   bf16 [256][1152]        =    589,824 B (conv1 w)
//   [31,670,272) wToffm bf16 [2][72][512]      =    147,456 B (off w, MFMA-fragment-major)
//   [31,836,160) xN    bf16 [8][25600pix][128c]= 52,428,800 B

typedef __hip_bfloat16 bf16;
typedef __attribute__((ext_vector_type(8))) short short8;
typedef __attribute__((ext_vector_type(4))) float float4v;

#define EPSBN 1e-5f

__device__ __forceinline__ float bf2f(bf16 x){ return __bfloat162float(x); }
__device__ __forceinline__ float bits2f(unsigned short u){ return __uint_as_float(((unsigned)u) << 16); }
__device__ __forceinline__ float silu_(float x){ return x / (1.f + __expf(-x)); }
__device__ __forceinline__ unsigned short f2bf_bits(float f){
    union { float f; unsigned u; } uf; uf.f = f;
    unsigned r = uf.u + 0x7fff + ((uf.u >> 16) & 1);   // RNE (finite inputs)
    return (unsigned short)(r >> 16);
}

// ---------------------------------------------------------------------------
// K0a: dconv_w [256oc][256c][9tap] fp32 -> wb2 bf16 [256oc][2304], kk = tap*256+c.
__global__ __launch_bounds__(256) void k_wdprep(const float* __restrict__ w, bf16* __restrict__ wb2)
{
    int idx = blockIdx.x * 256 + threadIdx.x;
    if (idx >= 256 * 2304) return;
    int oc  = idx / 2304;
    int r   = idx - oc * 2304;
    int tap = r >> 8;
    int c   = r & 255;
    wb2[idx] = __float2bfloat16(w[(oc * 256 + c) * 9 + tap]);
}

// K0b (primary): conv1 weights -> bf16 TAP-MAJOR [oc][tap*128+c].
__global__ __launch_bounds__(256) void k_wprep1t(const float* __restrict__ w, bf16* __restrict__ wb)
{
    int idx = blockIdx.x * 256 + threadIdx.x;      // 294,912
    if (idx >= 256 * 1152) return;
    int oc  = idx / 1152;
    int r   = idx - oc * 1152;
    int tap = r >> 7;
    int c   = r & 127;
    wb[idx] = __float2bfloat16(w[(oc * 128 + c) * 9 + tap]);
}

// K0b' (fallback): conv1 weights -> bf16, c-major [oc][c*9+tap] (round-6).
__global__ __launch_bounds__(256) void k_wprep(const float* __restrict__ w, bf16* __restrict__ wb)
{
    int idx = blockIdx.x * 256 + threadIdx.x;
    if (idx >= 256 * 1152) return;
    wb[idx] = __float2bfloat16(w[idx]);
}

// K0c: off_w [18oc][256c][9tap] fp32 -> wToffm bf16 MFMA-FRAGMENT-MAJOR (r18).
__global__ __launch_bounds__(256) void k_woprepm(const float* __restrict__ w, bf16* __restrict__ wm)
{
    int idx = blockIdx.x * 256 + threadIdx.x;      // 73,728
    if (idx >= 2 * 72 * 512) return;
    int j    = idx & 7;
    int lane = (idx >> 3) & 63;
    int frag = idx >> 9;                           // 0..143
    int half = frag / 72;
    int kc   = frag - half * 72;
    int oc   = half * 16 + (lane & 15);
    int kk   = kc * 32 + (lane >> 4) * 8 + j;
    int tap  = kk >> 8;
    int c    = kk & 255;
    float v  = (oc < 18) ? w[(oc * 256 + c) * 9 + tap] : 0.f;
    wm[idx] = __float2bfloat16(v);
}

// K0d: x NCHW fp32 -> xN NHWC bf16 via LDS tile transpose.
__global__ __launch_bounds__(256) void k_xprep(const float* __restrict__ x, bf16* __restrict__ xN)
{
    __shared__ short sm[64 * 132];                 // 16,896 B
    const int tid  = threadIdx.x;
    const int b    = blockIdx.x / 400;             // 3200 blocks
    const int pix0 = (blockIdx.x % 400) * 64;
    const int lane = tid & 63;
    const int wq   = tid >> 6;
    const float* xb = x + (size_t)b * 128 * 25600;

    #pragma unroll
    for (int i = 0; i < 32; i++){
        int c = i * 4 + wq;
        sm[lane * 132 + c] = (short)f2bf_bits(xb[c * 25600 + pix0 + lane]);
    }
    __syncthreads();

    bf16* xo = xN + ((size_t)b * 25600 + pix0) * 128;
    #pragma unroll
    for (int j = 0; j < 8; j++){
        int idx = j * 256 + tid;                   // 0..2047
        int p = idx >> 5, q = idx & 31;
        *reinterpret_cast<ushort4*>(xo + p * 128 + q * 4) =
            *reinterpret_cast<const ushort4*>(&sm[p * 132 + q * 4]);
    }
}

// ---------------------------------------------------------------------------
// K1 (primary): conv1 (3x3 s2 p1) + BN1 + SiLU, MFMA implicit GEMM on NHWC xN.
// Round-19: 128-pixel N-tile (400 blocks), register-prefetch pipeline, XCD
// swizzle. Per iter: 32 MFMA/wave (acc[4][8]); B-stage = 2 masked 16B loads.
__global__ __launch_bounds__(256) void k_conv1n(
    const bf16* __restrict__ xN, const bf16* __restrict__ wb,
    const float* __restrict__ g, const float* __restrict__ bb,
    const float* __restrict__ mm, const float* __restrict__ vv,
    bf16* __restrict__ hN)
{
    __shared__ short A_lds[256 * 40];              // 20,480 B
    __shared__ short B_lds[128 * 40];              // 10,240 B
    __shared__ unsigned short nidx[1152];          //  2,304 B
    __shared__ unsigned short nmsk[1152];          //  2,304 B
    __shared__ float sc_s[256], sh_s[256];         //  2,048 B  -> 37,376 B

    const int tid  = threadIdx.x;
    const int b    = blockIdx.x & 7;               // XCD-aligned (400 = 8*50)
    const int pix0 = (blockIdx.x >> 3) * 128;
    const bf16* xb = xN + (size_t)b * 25600 * 128;

    {
        float scv = g[tid] * rsqrtf(vv[tid] + EPSBN);
        sc_s[tid] = scv;
        sh_s[tid] = bb[tid] - mm[tid] * scv;
    }

    for (int e = tid; e < 1152; e += 256){
        int t = e & 127, k = e >> 7;
        int pix = pix0 + t;
        int oh = pix / 80, ow = pix % 80;
        int ih = 2 * oh + k / 3 - 1;
        int iw = 2 * ow + k % 3 - 1;
        nmsk[e] = ((ih | iw) >= 0) ? 1 : 0;
        nidx[e] = (unsigned short)(max(ih, 0) * 160 + max(iw, 0));
    }
    __syncthreads();

    const int t4   = tid >> 2;                     // pixel slot 0..63 (pixels t4, t4+64)
    const int cq   = tid & 3;                      // channel octet
    const int wv   = tid >> 6;
    const int lane = tid & 63;
    const int lrow = lane & 15;
    const int quad = lane >> 4;
    const int ocA  = tid >> 2;                     // A-stage row
    const int kqA  = tid & 3;

    uint4  pa0, pa1, pa2, pa3;                     // A prefetch regs
    short8 pb0, pb1;                               // B prefetch regs (2 pixels)

    float4v acc[4][8];
    #pragma unroll
    for (int i = 0; i < 4; i++)
        #pragma unroll
        for (int j = 0; j < 8; j++)
            acc[i][j] = (float4v){0.f, 0.f, 0.f, 0.f};

    auto issue_pref = [&](int kc){
        const bf16* wp = wb + kc * 32 + kqA * 8;
        pa0 = *reinterpret_cast<const uint4*>(wp + (0 * 64 + ocA) * 1152);
        pa1 = *reinterpret_cast<const uint4*>(wp + (1 * 64 + ocA) * 1152);
        pa2 = *reinterpret_cast<const uint4*>(wp + (2 * 64 + ocA) * 1152);
        pa3 = *reinterpret_cast<const uint4*>(wp + (3 * 64 + ocA) * 1152);
        const int tap = kc >> 2;
        const int cb  = (kc & 3) * 32 + cq * 8;
        #pragma unroll
        for (int s = 0; s < 2; s++){
            const int e  = tap * 128 + t4 + s * 64;
            const int sp = (int)nidx[e];
            const bool mv = nmsk[e] != 0;
            short8 v = {0, 0, 0, 0, 0, 0, 0, 0};
            if (mv) v = *reinterpret_cast<const short8*>(xb + (size_t)sp * 128 + cb);
            if (s == 0) pb0 = v; else pb1 = v;
        }
    };
    auto write_stage = [&](){
        *reinterpret_cast<uint4*>(&A_lds[(0 * 64 + ocA) * 40 + kqA * 8]) = pa0;
        *reinterpret_cast<uint4*>(&A_lds[(1 * 64 + ocA) * 40 + kqA * 8]) = pa1;
        *reinterpret_cast<uint4*>(&A_lds[(2 * 64 + ocA) * 40 + kqA * 8]) = pa2;
        *reinterpret_cast<uint4*>(&A_lds[(3 * 64 + ocA) * 40 + kqA * 8]) = pa3;
        *reinterpret_cast<short8*>(&B_lds[(t4     ) * 40 + cq * 8]) = pb0;
        *reinterpret_cast<short8*>(&B_lds[(t4 + 64) * 40 + cq * 8]) = pb1;
    };

    issue_pref(0);
    write_stage();
    __syncthreads();

    for (int kc = 0; kc < 36; kc++){
        if (kc < 35) issue_pref(kc + 1);           // in-flight across the MFMA block

        short8 af[4];
        #pragma unroll
        for (int i = 0; i < 4; i++){
            int row = wv * 64 + i * 16 + lrow;
            af[i] = *reinterpret_cast<const short8*>(&A_lds[row * 40 + quad * 8]);
        }
        #pragma unroll
        for (int j = 0; j < 8; j++){
            short8 bfv = *reinterpret_cast<const short8*>(&B_lds[(j * 16 + lrow) * 40 + quad * 8]);
            #pragma unroll
            for (int i = 0; i < 4; i++)
                acc[i][j] = __builtin_amdgcn_mfma_f32_16x16x32_bf16(af[i], bfv, acc[i][j], 0, 0, 0);
        }

        if (kc < 35){
            __syncthreads();                       // all reads of kc done
            write_stage();                         // stage kc+1
            __syncthreads();                       // kc+1 ready
        }
    }

    #pragma unroll
    for (int i = 0; i < 4; i++){
        int oc0 = wv * 64 + i * 16 + quad * 4;
        float s0 = sc_s[oc0+0], h0 = sh_s[oc0+0];
        float s1 = sc_s[oc0+1], h1 = sh_s[oc0+1];
        float s2 = sc_s[oc0+2], h2 = sh_s[oc0+2];
        float s3 = sc_s[oc0+3], h3 = sh_s[oc0+3];
        #pragma unroll
        for (int j = 0; j < 8; j++){
            int pix = pix0 + j * 16 + lrow;
            ushort4 o;
            o.x = f2bf_bits(silu_(acc[i][j][0] * s0 + h0));
            o.y = f2bf_bits(silu_(acc[i][j][1] * s1 + h1));
            o.z = f2bf_bits(silu_(acc[i][j][2] * s2 + h2));
            o.w = f2bf_bits(silu_(acc[i][j][3] * s3 + h3));
            *reinterpret_cast<ushort4*>(hN + ((size_t)b * 6400 + pix) * 256 + oc0) = o;
        }
    }
}

// K1 (fallback): round-6 conv1 on NCHW fp32 x (validated), verbatim.
__global__ __launch_bounds__(256) void k_conv1(
    const float* __restrict__ x, const bf16* __restrict__ wb,
    const float* __restrict__ g, const float* __restrict__ bb,
    const float* __restrict__ mm, const float* __restrict__ vv,
    bf16* __restrict__ hN)
{
    __shared__ short A_lds[256 * 40];
    __shared__ short B_lds[64 * 40];
    __shared__ float sc_s[256], sh_s[256];

    const int tid  = threadIdx.x;
    const int b    = blockIdx.x / 100;
    const int pix0 = (blockIdx.x % 100) * 64;
    const float* xb = x + b * (128 * 25600);

    {
        float scv = g[tid] * rsqrtf(vv[tid] + EPSBN);
        sc_s[tid] = scv;
        sh_s[tid] = bb[tid] - mm[tid] * scv;
    }

    const int k_in = tid & 31;
    const int prow = tid >> 5;
    int oh8[8], ow8[8];
    #pragma unroll
    for (int p = 0; p < 8; p++){
        int pix = pix0 + prow + p * 8;
        oh8[p] = pix / 80; ow8[p] = pix % 80;
    }

    const int wv   = tid >> 6;
    const int lane = tid & 63;
    const int lrow = lane & 15;
    const int quad = lane >> 4;

    float4v acc[4][4];
    #pragma unroll
    for (int i = 0; i < 4; i++)
        #pragma unroll
        for (int j = 0; j < 4; j++)
            acc[i][j] = (float4v){0.f, 0.f, 0.f, 0.f};

    for (int kc = 0; kc < 36; kc++){
        const int k0 = kc * 32;
        __syncthreads();

        #pragma unroll
        for (int p2 = 0; p2 < 4; p2++){
            int idx = p2 * 256 + tid;
            int oc  = idx >> 2;
            int kq  = idx & 3;
            *reinterpret_cast<uint4*>(&A_lds[oc * 40 + kq * 8]) =
                *reinterpret_cast<const uint4*>(wb + oc * 1152 + k0 + kq * 8);
        }

        {
            int kk  = k0 + k_in;
            int c   = kk / 9;
            int tap = kk - 9 * c;
            int kh  = tap / 3 - 1;
            int kw  = tap - 3 * (tap / 3) - 1;
            const float* xc = xb + c * 25600;
            #pragma unroll
            for (int p = 0; p < 8; p++){
                int ih = 2 * oh8[p] + kh;
                int iw = 2 * ow8[p] + kw;
                float v = 0.f;
                if ((ih | iw) >= 0) v = xc[ih * 160 + iw];
                B_lds[(prow + p * 8) * 40 + k_in] = (short)f2bf_bits(v);
            }
        }
        __syncthreads();

        short8 af[4], bfv[4];
        #pragma unroll
        for (int i = 0; i < 4; i++){
            int row = wv * 64 + i * 16 + lrow;
            af[i] = *reinterpret_cast<const short8*>(&A_lds[row * 40 + quad * 8]);
        }
        #pragma unroll
        for (int j = 0; j < 4; j++){
            bfv[j] = *reinterpret_cast<const short8*>(&B_lds[(j * 16 + lrow) * 40 + quad * 8]);
        }
        #pragma unroll
        for (int i = 0; i < 4; i++)
            #pragma unroll
            for (int j = 0; j < 4; j++)
                acc[i][j] = __builtin_amdgcn_mfma_f32_16x16x32_bf16(af[i], bfv[j], acc[i][j], 0, 0, 0);
    }

    #pragma unroll
    for (int i = 0; i < 4; i++){
        int oc0 = wv * 64 + i * 16 + quad * 4;
        float s0 = sc_s[oc0+0], h0 = sh_s[oc0+0];
        float s1 = sc_s[oc0+1], h1 = sh_s[oc0+1];
        float s2 = sc_s[oc0+2], h2 = sh_s[oc0+2];
        float s3 = sc_s[oc0+3], h3 = sh_s[oc0+3];
        #pragma unroll
        for (int j = 0; j < 4; j++){
            int pix = pix0 + j * 16 + lrow;
            ushort4 o;
            o.x = f2bf_bits(silu_(acc[i][j][0] * s0 + h0));
            o.y = f2bf_bits(silu_(acc[i][j][1] * s1 + h1));
            o.z = f2bf_bits(silu_(acc[i][j][2] * s2 + h2));
            o.w = f2bf_bits(silu_(acc[i][j][3] * s3 + h3));
            *reinterpret_cast<ushort4*>(hN + (b * 6400 + pix) * 256 + oc0) = o;
        }
    }
}

// ---------------------------------------------------------------------------
// K2: offset conv as barrier-free MFMA — round-20: 32 pixels/wave (2 B-frags
// per A-pair, 4 MFMA per A-load) to halve A-fragment L2 traffic. 400 blocks.
__global__ __launch_bounds__(256) void k_off_m(
    const bf16* __restrict__ hN, const bf16* __restrict__ wm,
    const float* __restrict__ bias, float* __restrict__ off)
{
    const int tid  = threadIdx.x;
    const int b    = blockIdx.x & 7;               // XCD-aligned (400 = 8*50)
    const int pixb = (blockIdx.x >> 3) * 128 + (tid >> 6) * 32;  // wave's 32 pixels
    const int lane = tid & 63;
    const int l15  = lane & 15;
    const int ksl  = lane >> 4;
    const bf16* hb = hN + b * (6400 * 256);

    int oh0, ow0, oh1, ow1;
    {
        int p0 = pixb + l15;       oh0 = p0 / 80; ow0 = p0 % 80;
        int p1 = pixb + 16 + l15;  oh1 = p1 / 80; ow1 = p1 % 80;
    }

    float4v acc0_0 = {0.f,0.f,0.f,0.f}, acc1_0 = {0.f,0.f,0.f,0.f};
    float4v acc0_1 = {0.f,0.f,0.f,0.f}, acc1_1 = {0.f,0.f,0.f,0.f};

    for (int tap = 0; tap < 9; tap++){
        const int kh = tap / 3 - 1, kw = tap % 3 - 1;
        const int ih0 = oh0 + kh, iw0 = ow0 + kw;
        const int ih1 = oh1 + kh, iw1 = ow1 + kw;
        const bool v0 = ((unsigned)ih0 < 80u) && ((unsigned)iw0 < 80u);
        const bool v1 = ((unsigned)ih1 < 80u) && ((unsigned)iw1 < 80u);
        const bf16* hp0 = hb + (size_t)(v0 ? (ih0 * 80 + iw0) : 0) * 256 + ksl * 8;
        const bf16* hp1 = hb + (size_t)(v1 ? (ih1 * 80 + iw1) : 0) * 256 + ksl * 8;
        const bf16* wp  = wm + (size_t)tap * 8 * 512 + lane * 8;
        #pragma unroll
        for (int sub = 0; sub < 8; sub++){
            short8 a0 = *reinterpret_cast<const short8*>(wp + sub * 512);
            short8 a1 = *reinterpret_cast<const short8*>(wp + 72 * 512 + sub * 512);
            short8 b0 = {0,0,0,0,0,0,0,0}, b1 = {0,0,0,0,0,0,0,0};
            if (v0) b0 = *reinterpret_cast<const short8*>(hp0 + sub * 32);
            if (v1) b1 = *reinterpret_cast<const short8*>(hp1 + sub * 32);
            acc0_0 = __builtin_amdgcn_mfma_f32_16x16x32_bf16(a0, b0, acc0_0, 0, 0, 0);
            acc1_0 = __builtin_amdgcn_mfma_f32_16x16x32_bf16(a1, b0, acc1_0, 0, 0, 0);
            acc0_1 = __builtin_amdgcn_mfma_f32_16x16x32_bf16(a0, b1, acc0_1, 0, 0, 0);
            acc1_1 = __builtin_amdgcn_mfma_f32_16x16x32_bf16(a1, b1, acc1_1, 0, 0, 0);
        }
    }

    // C layout: col(pixel) = lane&15, row(oc) = (lane>>4)*4 + r  (+16 for acc1)
    #pragma unroll
    for (int r = 0; r < 4; r++){
        int oc = ksl * 4 + r;
        off[((size_t)b * 18 + oc) * 6400 + pixb + l15]      = acc0_0[r] + bias[oc];
        off[((size_t)b * 18 + oc) * 6400 + pixb + 16 + l15] = acc0_1[r] + bias[oc];
    }
    if (ksl == 0){
        #pragma unroll
        for (int r = 0; r < 2; r++){
            int oc = 16 + r;
            off[((size_t)b * 18 + oc) * 6400 + pixb + l15]      = acc1_0[r] + bias[oc];
            off[((size_t)b * 18 + oc) * 6400 + pixb + 16 + l15] = acc1_1[r] + bias[oc];
        }
    }
}

// ---------------------------------------------------------------------------
// K3: deform conv MFMA on NHWC h — r15-exact (validated 176.6us).
__global__ __launch_bounds__(256) void k_dconv_nhwc(
    const bf16* __restrict__ hN, const float* __restrict__ off,
    const bf16* __restrict__ wb2,
    const float* __restrict__ g, const float* __restrict__ bb,
    const float* __restrict__ mm, const float* __restrict__ vv,
    float* __restrict__ out)
{
    __shared__ short   A_lds[256 * 40];            // 20,480 B
    __shared__ short   B_lds[64 * 40];             //  5,120 B
    __shared__ ushort4 sidxu[576];                 //  4,608 B
    __shared__ ushort4 swtu [576];                 //  4,608 B
    __shared__ float   sc_s[256], sh_s[256];       //  2,048 B  -> 36,864 B total

    const int tid  = threadIdx.x;
    const int b    = blockIdx.x & 7;               // XCD-aligned (800 = 8*100)
    const int pix0 = (blockIdx.x >> 3) * 64;
    const bf16* hb = hN + b * (6400 * 256);

    {
        float scv = g[tid] * rsqrtf(vv[tid] + EPSBN);
        sc_s[tid] = scv;
        sh_s[tid] = bb[tid] - mm[tid] * scv;
    }

    for (int e = tid; e < 576; e += 256){
        int t = e & 63, k = e >> 6;
        int pix = pix0 + t;
        int oh = pix / 80, ow = pix % 80;
        int kh = k / 3, kw = k % 3;
        float oy = off[(b * 18 + 2 * k    ) * 6400 + pix];
        float ox = off[(b * 18 + 2 * k + 1) * 6400 + pix];
        float py = (float)(oh + kh - 1) + oy;
        float px = (float)(ow + kw - 1) + ox;
        float y0f = floorf(py), x0f = floorf(px);
        float wy1 = py - y0f,  wx1 = px - x0f;
        int y0 = (int)y0f, x0 = (int)x0f;
        unsigned short ii[4], ww[4];
        #pragma unroll
        for (int cy = 0; cy < 2; cy++){
            int   yy = y0 + cy;
            float wy = cy ? wy1 : 1.f - wy1;
            bool  vy = (yy >= 0) && (yy < 80);
            int   yc = min(max(yy, 0), 79);
            #pragma unroll
            for (int cx = 0; cx < 2; cx++){
                int   xx = x0 + cx;
                float wx = cx ? wx1 : 1.f - wx1;
                bool  vx = (xx >= 0) && (xx < 80);
                int   xc = min(max(xx, 0), 79);
                int ci = cy * 2 + cx;
                ii[ci] = (unsigned short)(yc * 80 + xc);
                ww[ci] = f2bf_bits((vy && vx) ? wy * wx : 0.f);
            }
        }
        ushort4 iv; iv.x = ii[0]; iv.y = ii[1]; iv.z = ii[2]; iv.w = ii[3];
        ushort4 wv_; wv_.x = ww[0]; wv_.y = ww[1]; wv_.z = ww[2]; wv_.w = ww[3];
        sidxu[e] = iv;
        swtu [e] = wv_;
    }
    __syncthreads();

    const int t4   = tid >> 2;                     // pixel 0..63
    const int cq   = tid & 3;                      // channel octet (8 contiguous ch in sub)
    const int wv   = tid >> 6;
    const int lane = tid & 63;
    const int lrow = lane & 15;
    const int quad = lane >> 4;
    const int ocA  = tid >> 2;                     // A-stage row base
    const int kqA  = tid & 3;

    const bf16* wA = wb2 + (size_t)ocA * 2304 + kqA * 8;

    float w0, w1, w2, w3;
    const bf16 *p0, *p1, *p2, *p3;
    auto load_tap_state = [&](int tap){
        const int e = tap * 64 + t4;
        ushort4 ipk = sidxu[e];
        ushort4 wpk = swtu[e];
        w0 = bits2f(wpk.x); w1 = bits2f(wpk.y);
        w2 = bits2f(wpk.z); w3 = bits2f(wpk.w);
        p0 = hb + (int)ipk.x * 256 + cq * 8;
        p1 = hb + (int)ipk.y * 256 + cq * 8;
        p2 = hb + (int)ipk.z * 256 + cq * 8;
        p3 = hb + (int)ipk.w * 256 + cq * 8;
    };

    uint4  pa0, pa1, pa2, pa3;                     // A prefetch regs
    short8 pb0, pb1, pb2, pb3;                     // B gather prefetch regs

    auto issue_pref = [&](int kc){
        const bf16* wp = wA + kc * 32;
        pa0 = *reinterpret_cast<const uint4*>(wp);
        pa1 = *reinterpret_cast<const uint4*>(wp + (size_t)64 * 2304);
        pa2 = *reinterpret_cast<const uint4*>(wp + (size_t)128 * 2304);
        pa3 = *reinterpret_cast<const uint4*>(wp + (size_t)192 * 2304);
        const int co = (kc & 7) * 32;
        pb0 = *reinterpret_cast<const short8*>(p0 + co);
        pb1 = *reinterpret_cast<const short8*>(p1 + co);
        pb2 = *reinterpret_cast<const short8*>(p2 + co);
        pb3 = *reinterpret_cast<const short8*>(p3 + co);
    };

    float4v acc[4][4];
    #pragma unroll
    for (int i = 0; i < 4; i++)
        #pragma unroll
        for (int j = 0; j < 4; j++)
            acc[i][j] = (float4v){0.f, 0.f, 0.f, 0.f};

    load_tap_state(0);
    issue_pref(0);

    for (int tap = 0; tap < 9; tap++){
        for (int sub = 0; sub < 8; sub++){
            const int kc = tap * 8 + sub;

            // blend for kc (waits pb vmcnt — issued one MFMA block ago)
            short8 ob;
            #pragma unroll
            for (int el = 0; el < 8; el++){
                float f = w0 * bits2f((unsigned short)pb0[el])
                        + w1 * bits2f((unsigned short)pb1[el])
                        + w2 * bits2f((unsigned short)pb2[el])
                        + w3 * bits2f((unsigned short)pb3[el]);
                ob[el] = (short)f2bf_bits(f);
            }

            __syncthreads();                       // prev iter's ds_reads done

            // stage kc
            *reinterpret_cast<uint4*>(&A_lds[(0 * 64 + ocA) * 40 + kqA * 8]) = pa0;
            *reinterpret_cast<uint4*>(&A_lds[(1 * 64 + ocA) * 40 + kqA * 8]) = pa1;
            *reinterpret_cast<uint4*>(&A_lds[(2 * 64 + ocA) * 40 + kqA * 8]) = pa2;
            *reinterpret_cast<uint4*>(&A_lds[(3 * 64 + ocA) * 40 + kqA * 8]) = pa3;
            *reinterpret_cast<short8*>(&B_lds[t4 * 40 + cq * 8]) = ob;

            __syncthreads();                       // kc staged

            // prefetch kc+1 (cheap: imm offsets; new tap state once per 8)
            if (kc < 71){
                if (sub == 7) load_tap_state(tap + 1);
                issue_pref(kc + 1);
            }

            // MFMA for kc — covers the just-issued loads
            short8 af[4], bfv[4];
            #pragma unroll
            for (int i = 0; i < 4; i++){
                int row = wv * 64 + i * 16 + lrow;
                af[i] = *reinterpret_cast<const short8*>(&A_lds[row * 40 + quad * 8]);
            }
            #pragma unroll
            for (int j = 0; j < 4; j++){
                bfv[j] = *reinterpret_cast<const short8*>(&B_lds[(j * 16 + lrow) * 40 + quad * 8]);
            }
            #pragma unroll
            for (int i = 0; i < 4; i++)
                #pragma unroll
                for (int j = 0; j < 4; j++)
                    acc[i][j] = __builtin_amdgcn_mfma_f32_16x16x32_bf16(af[i], bfv[j], acc[i][j], 0, 0, 0);
        }
    }

    #pragma unroll
    for (int i = 0; i < 4; i++){
        #pragma unroll
        for (int r = 0; r < 4; r++){
            int oc = wv * 64 + i * 16 + quad * 4 + r;
            float scv = sc_s[oc], shv = sh_s[oc];
            #pragma unroll
            for (int j = 0; j < 4; j++){
                int pix = pix0 + j * 16 + lrow;
                out[(b * 256 + oc) * 6400 + pix] = silu_(acc[i][j][r] * scv + shv);
            }
        }
    }
}

// ---------------------------------------------------------------------------
extern "C" void kernel_launch(void* const* d_in, const int* in_sizes, int n_in,
                              void* d_out, int out_size, void* d_ws, size_t ws_size,
                              hipStream_t stream)
{
    (void)in_sizes; (void)n_in; (void)out_size;

    const float* x  = (const float*)d_in[0];
    const float* w1 = (const float*)d_in[1];
    const float* g1 = (const float*)d_in[2];
    const float* b1 = (const float*)d_in[3];
    const float* m1 = (const float*)d_in[4];
    const float* v1 = (const float*)d_in[5];
    const float* wo = (const float*)d_in[6];
    const float* bo = (const float*)d_in[7];
    const float* wd = (const float*)d_in[8];
    const float* g2 = (const float*)d_in[9];
    const float* b2 = (const float*)d_in[10];
    const float* m2 = (const float*)d_in[11];
    const float* v2 = (const float*)d_in[12];
    float* outp = (float*)d_out;

    char*  wsb  = (char*)d_ws;
    bf16*  hNb  = (bf16*) wsb;                      // 26,214,400 B
    float* obuf = (float*)(wsb + 26214400);         //  3,686,400 B
    bf16*  wb2b = (bf16*) (wsb + 29900800);         //  1,179,648 B
    bf16*  wbb  = (bf16*) (wsb + 31080448);         //    589,824 B
    bf16*  wmof = (bf16*) (wsb + 31670272);         //    147,456 B (<= 165,888 slot)
    bf16*  xNb  = (bf16*) (wsb + 31836160);         // 52,428,800 B

    const size_t need_primary = 84264960;

    hipLaunchKernelGGL(k_wdprep,  dim3(2304), dim3(256), 0, stream, wd, wb2b);
    hipLaunchKernelGGL(k_woprepm, dim3(288),  dim3(256), 0, stream, wo, wmof);

    if (ws_size >= need_primary){
        hipLaunchKernelGGL(k_wprep1t, dim3(1152), dim3(256), 0, stream, w1, wbb);
        hipLaunchKernelGGL(k_xprep,   dim3(3200), dim3(256), 0, stream, x, xNb);
        hipLaunchKernelGGL(k_conv1n,  dim3(400),  dim3(256), 0, stream, xNb, wbb, g1, b1, m1, v1, hNb);
    } else {
        hipLaunchKernelGGL(k_wprep,   dim3(1152), dim3(256), 0, stream, w1, wbb);
        hipLaunchKernelGGL(k_conv1,   dim3(800),  dim3(256), 0, stream, x, wbb, g1, b1, m1, v1, hNb);
    }

    hipLaunchKernelGGL(k_off_m,     dim3(400), dim3(256), 0, stream, hNb, wmof, bo, obuf);
    hipLaunchKernelGGL(k_dconv_nhwc,dim3(800), dim3(256), 0, stream, hNb, obuf, wb2b, g2, b2, m2, v2, outp);
}